// Round 6
// baseline (1492.961 us; speedup 1.0000x reference)
//
#include <hip/hip_runtime.h>

#define FLTMAX 3.402823466e+38f
#define DEV __device__ __forceinline__

typedef unsigned short u16;
typedef unsigned int u32;
typedef __bf16 bf16_t;
typedef bf16_t bf16x8 __attribute__((ext_vector_type(8)));
typedef float f32x4 __attribute__((ext_vector_type(4)));

union U16x8 { uint4 u; bf16x8 b; };

DEV float trf(float v, float a, float b) { return fmaxf(fmaf(v, a, b), 0.f); }

// sign-folded min helpers: track min of (v ^ sm); sm=0x80000000 turns it into max-tracking
DEV float sfmin(float m, float v, u32 sm) {
    return fminf(m, __uint_as_float(__float_as_uint(v) ^ sm));
}
DEV float sdec(float m, u32 sm) { return __uint_as_float(__float_as_uint(m) ^ sm); }

// round-to-nearest-even fp32 -> bf16 bits (finite inputs)
DEV u16 f2bf(float f) {
    u32 u = __float_as_uint(f);
    return (u16)((u + 0x7FFFu + ((u >> 16) & 1u)) >> 16);
}

// BN coef from stats: a = rsqrt(var+eps)*g, b = beta - mu*a
DEV void bncoef(float s, float s2, float g, float be, float invN, float& a, float& b) {
    const float mu = s * invN;
    const float var = s2 * invN - mu * mu;
    a = rsqrtf(var + 1e-5f) * g;
    b = be - mu * a;
}

// ================= CSR build =================
// XCD-partitioned histogram: same dst-range partition as csr_fill (atomics stay XCD-local)
__global__ __launch_bounds__(256) void hist_part_k(const int* __restrict__ dst,
                                                   int* __restrict__ deg, int E, int lo_step) {
    const int part = blockIdx.x & 7;
    const int e = (blockIdx.x >> 3) * 256 + threadIdx.x;
    if (e >= E) return;
    const int d = dst[e];
    const int lo = part * lo_step;
    const int hi = lo + lo_step;
    if (d < lo || d >= hi) return;
    atomicAdd(&deg[d], 1);
}

__global__ __launch_bounds__(256) void scan_block_k(const int* __restrict__ deg,
                                                    int* __restrict__ ptr,
                                                    int* __restrict__ bsum, int n) {
    __shared__ int ls[256];
    int i = blockIdx.x * 256 + threadIdx.x;
    int v = (i < n) ? deg[i] : 0;
    ls[threadIdx.x] = v;
    __syncthreads();
#pragma unroll
    for (int off = 1; off < 256; off <<= 1) {
        int a = (threadIdx.x >= off) ? ls[threadIdx.x - off] : 0;
        __syncthreads();
        ls[threadIdx.x] += a;
        __syncthreads();
    }
    if (i < n) ptr[i] = ls[threadIdx.x] - v;
    if (threadIdx.x == 255) bsum[blockIdx.x] = ls[255];
}

// scan_add with inline prefix over raw bsum
__global__ __launch_bounds__(256) void scan_add_k(int* __restrict__ ptr,
                                                  int* __restrict__ pos,
                                                  const int* __restrict__ bsum,
                                                  int n, int E) {
    __shared__ int shw[4];
    const int tid = threadIdx.x;
    int part = 0;
    for (int k = tid; k < blockIdx.x; k += 256) part += bsum[k];
#pragma unroll
    for (int off = 1; off < 64; off <<= 1) part += __shfl_xor(part, off);
    if ((tid & 63) == 0) shw[tid >> 6] = part;
    __syncthreads();
    const int boff = shw[0] + shw[1] + shw[2] + shw[3];
    const int i = blockIdx.x * 256 + tid;
    if (i == 0) ptr[n] = E;
    if (i < n) {
        int p = ptr[i] + boff;
        ptr[i] = p;
        pos[i] = p;
    }
}

// XCD-partitioned fill: partition = blockIdx & 7
__global__ __launch_bounds__(256) void csr_fill_part_k(
    const int* __restrict__ src, const int* __restrict__ dst,
    int* __restrict__ pos, int* __restrict__ csr, int E, int lo_step) {
    const int part = blockIdx.x & 7;
    const int e = (blockIdx.x >> 3) * 256 + threadIdx.x;
    if (e >= E) return;
    const int d = dst[e];
    const int lo = part * lo_step;
    const int hi = lo + lo_step;
    if (d < lo || d >= hi) return;
    const int p = atomicAdd(&pos[d], 1);
    csr[p] = src[e];
}

// ====== fp32 gather min (layer-1 x, D=32) ======
__global__ __launch_bounds__(256) void gather_min32_k(
    const float* __restrict__ feat, const int* __restrict__ ptr,
    const int* __restrict__ csr, float* __restrict__ agg, int n) {
    const int lane = threadIdx.x & 63;
    const int wave = (blockIdx.x * 256 + threadIdx.x) >> 6;
    const int node = wave * 2 + (lane >> 5);
    if (node >= n) return;
    const int fl = lane & 31;
    int e = ptr[node];
    const int end = ptr[node + 1];
    const bool empty = (e == end);
    float m = FLTMAX;
    for (; e + 7 < end; e += 8) {
        int s[8];
#pragma unroll
        for (int j = 0; j < 8; j++) s[j] = csr[e + j];
        float v[8];
#pragma unroll
        for (int j = 0; j < 8; j++) v[j] = feat[(size_t)s[j] * 32 + fl];
#pragma unroll
        for (int j = 0; j < 8; j++) m = fminf(m, v[j]);
    }
    for (; e < end; e++) m = fminf(m, feat[(size_t)csr[e] * 32 + fl]);
    agg[(size_t)node * 32 + fl] = empty ? 0.f : m;
}

// ====== fp32 gather min D=128, fused BN+ReLU (sign-folded) ======
// 1 node per 64-lane wave, float2/lane. Inline coef from stats; block0 exports coef1.
__global__ __launch_bounds__(256) void gather_min128_k(
    const float* __restrict__ feat, const int* __restrict__ ptr,
    const int* __restrict__ csr, const float* __restrict__ stats,
    const float* __restrict__ g, const float* __restrict__ be,
    float* __restrict__ coef_out, float* __restrict__ agg, float invN, int n) {
    const int lane = threadIdx.x & 63;
    const int node = (blockIdx.x * 256 + threadIdx.x) >> 6;
    if (node >= n) return;
    const int fl = lane * 2;
    float ca0, cb0, ca1, cb1;
    bncoef(stats[fl], stats[128 + fl], g[fl], be[fl], invN, ca0, cb0);
    bncoef(stats[fl + 1], stats[129 + fl], g[fl + 1], be[fl + 1], invN, ca1, cb1);
    if (blockIdx.x == 0 && threadIdx.x < 64) {   // export for linear2
        coef_out[fl] = ca0; coef_out[fl + 1] = ca1;
        coef_out[128 + fl] = cb0; coef_out[129 + fl] = cb1;
    }
    const u32 sm0 = (ca0 < 0.f) ? 0x80000000u : 0u;
    const u32 sm1 = (ca1 < 0.f) ? 0x80000000u : 0u;
    int e = ptr[node];
    const int end = ptr[node + 1];
    const bool empty = (e == end);
    float m0 = FLTMAX, m1 = FLTMAX;
    for (; e + 7 < end; e += 8) {
        int s[8];
#pragma unroll
        for (int j = 0; j < 8; j++) s[j] = csr[e + j];
        float2 v[8];
#pragma unroll
        for (int j = 0; j < 8; j++) v[j] = *(const float2*)(feat + (size_t)s[j] * 128 + fl);
#pragma unroll
        for (int j = 0; j < 8; j++) {
            m0 = sfmin(m0, v[j].x, sm0);
            m1 = sfmin(m1, v[j].y, sm1);
        }
    }
    for (; e + 3 < end; e += 4) {
        int s[4];
#pragma unroll
        for (int j = 0; j < 4; j++) s[j] = csr[e + j];
        float2 v[4];
#pragma unroll
        for (int j = 0; j < 4; j++) v[j] = *(const float2*)(feat + (size_t)s[j] * 128 + fl);
#pragma unroll
        for (int j = 0; j < 4; j++) {
            m0 = sfmin(m0, v[j].x, sm0);
            m1 = sfmin(m1, v[j].y, sm1);
        }
    }
    for (; e < end; e++) {
        const float2 v = *(const float2*)(feat + (size_t)csr[e] * 128 + fl);
        m0 = sfmin(m0, v.x, sm0);
        m1 = sfmin(m1, v.y, sm1);
    }
    float2 o;
    o.x = empty ? 0.f : trf(sdec(m0, sm0), ca0, cb0);
    o.y = empty ? 0.f : trf(sdec(m1, sm1), ca1, cb1);
    *(float2*)(agg + (size_t)node * 128 + fl) = o;
}

// ====== bf16 gather min over A_cat right half -> left half ======
// 2 nodes/wave: 32 lanes x uint2 (4 bf16) per neighbor row.
__global__ __launch_bounds__(256) void gather_bf_k(
    u16* __restrict__ Acat, const int* __restrict__ ptr,
    const int* __restrict__ csr, int n) {
    const int lane = threadIdx.x & 63;
    const int wave = (blockIdx.x * 256 + threadIdx.x) >> 6;
    const int node = wave * 2 + (lane >> 5);
    if (node >= n) return;
    const int fl = (lane & 31) * 4;   // u16 index; 32 lanes x 4 = 128 cols
    int e = ptr[node];
    const int end = ptr[node + 1];
    uint2 outv = {0u, 0u};
    if (e != end) {
        float m0 = FLTMAX, m1 = FLTMAX, m2 = FLTMAX, m3 = FLTMAX;
        for (; e + 7 < end; e += 8) {
            int s[8];
#pragma unroll
            for (int j = 0; j < 8; j++) s[j] = csr[e + j];
            uint2 v[8];
#pragma unroll
            for (int j = 0; j < 8; j++) v[j] = *(const uint2*)(Acat + (size_t)s[j] * 256 + 128 + fl);
#pragma unroll
            for (int j = 0; j < 8; j++) {
                m0 = fminf(m0, __uint_as_float(v[j].x << 16));
                m1 = fminf(m1, __uint_as_float(v[j].x & 0xffff0000u));
                m2 = fminf(m2, __uint_as_float(v[j].y << 16));
                m3 = fminf(m3, __uint_as_float(v[j].y & 0xffff0000u));
            }
        }
        for (; e < end; e++) {
            const uint2 v = *(const uint2*)(Acat + (size_t)csr[e] * 256 + 128 + fl);
            m0 = fminf(m0, __uint_as_float(v.x << 16));
            m1 = fminf(m1, __uint_as_float(v.x & 0xffff0000u));
            m2 = fminf(m2, __uint_as_float(v.y << 16));
            m3 = fminf(m3, __uint_as_float(v.y & 0xffff0000u));
        }
        outv.x = (__float_as_uint(m0) >> 16) | (__float_as_uint(m1) & 0xffff0000u);
        outv.y = (__float_as_uint(m2) >> 16) | (__float_as_uint(m3) & 0xffff0000u);
    }
    *(uint2*)(Acat + (size_t)node * 256 + fl) = outv;
}

// ====== convert bn_relu(h) (D=128) -> bf16 into A_cat right half (coef inlined) ======
__global__ __launch_bounds__(256) void convert_k(
    const float* __restrict__ h, const float* __restrict__ stats,
    const float* __restrict__ g, const float* __restrict__ be,
    u16* __restrict__ Acat, float invN, int n) {
    int t = blockIdx.x * 256 + threadIdx.x;
    int total = n * 32;
    if (t >= total) return;
    int i = t >> 5;
    int dq = (t & 31) * 4;
    const float4 s1 = *(const float4*)(stats + dq);
    const float4 s2 = *(const float4*)(stats + 128 + dq);
    const float4 gv = *(const float4*)(g + dq);
    const float4 ev = *(const float4*)(be + dq);
    float4 ca, cb;
    bncoef(s1.x, s2.x, gv.x, ev.x, invN, ca.x, cb.x);
    bncoef(s1.y, s2.y, gv.y, ev.y, invN, ca.y, cb.y);
    bncoef(s1.z, s2.z, gv.z, ev.z, invN, ca.z, cb.z);
    bncoef(s1.w, s2.w, gv.w, ev.w, invN, ca.w, cb.w);
    const float4 hv = *(const float4*)(h + (size_t)i * 128 + dq);
    ushort4 o;
    o.x = f2bf(trf(hv.x, ca.x, cb.x));
    o.y = f2bf(trf(hv.y, ca.y, cb.y));
    o.z = f2bf(trf(hv.z, ca.z, cb.z));
    o.w = f2bf(trf(hv.w, ca.w, cb.w));
    *(ushort4*)(Acat + (size_t)i * 256 + 128 + dq) = o;
}

// ====== weight prep (dual, one launch): WT row c: c<64 -> rt pair, else md pair ======
__global__ __launch_bounds__(256) void wprep_dual_k(
    const float* __restrict__ rwl, const float* __restrict__ rwr,
    const float* __restrict__ mwl, const float* __restrict__ mwr,
    u16* __restrict__ WT) {
    int t = blockIdx.x * 256 + threadIdx.x;   // 128*256 total
    int c = t >> 8;
    int k = t & 255;
    const float* wlp = (c < 64) ? rwl : mwl;
    const float* wrp = (c < 64) ? rwr : mwr;
    const int cc = c & 63;
    float v = (k < 128) ? wlp[k * 64 + cc] : wrp[(k - 128) * 64 + cc];
    WT[(size_t)c * 256 + k] = f2bf(v);
}

// ====== bf16 MFMA GEMM: out[n][128] = A_cat[n][256] @ W_cat[256][128] + bias ======
// per-block column stats accumulated directly into stats via atomics
__global__ __launch_bounds__(256) void gemm_bf_k(
    const u16* __restrict__ A, const u16* __restrict__ WT,
    const float* __restrict__ bl1, const float* __restrict__ bl2,
    float* __restrict__ out, float* __restrict__ stats, int n) {
    constexpr int NT = 8;
    __shared__ float bs[256];
    const int tid = threadIdx.x;
    bs[tid] = 0.f;
    const int wave = tid >> 6, lane = tid & 63;
    const int quad = lane >> 4, l16 = lane & 15;
    const int row0 = blockIdx.x * 64 + wave * 16;
    const int rowA = min(row0 + l16, n - 1);
    const uint4* Arow = (const uint4*)(A + (size_t)rowA * 256) + quad;

    bf16x8 a[8];
#pragma unroll
    for (int kc = 0; kc < 8; kc++) {
        U16x8 u; u.u = Arow[kc * 4];
        a[kc] = u.b;
    }
    f32x4 acc[NT];
#pragma unroll
    for (int i = 0; i < NT; i++) acc[i] = (f32x4){0.f, 0.f, 0.f, 0.f};
#pragma unroll
    for (int nt = 0; nt < NT; nt++) {
        const uint4* Brow = (const uint4*)(WT + (size_t)(nt * 16 + l16) * 256) + quad;
#pragma unroll
        for (int kc = 0; kc < 8; kc++) {
            U16x8 u; u.u = Brow[kc * 4];
            acc[nt] = __builtin_amdgcn_mfma_f32_16x16x32_bf16(a[kc], u.b, acc[nt], 0, 0, 0);
        }
    }
    __syncthreads();   // bs[] zeroed by all waves before atomics below
#pragma unroll
    for (int nt = 0; nt < NT; nt++) {
        const int col = nt * 16 + l16;
        const float bias = (col < 64) ? bl1[col] : bl2[col - 64];
        float s = 0.f, q = 0.f;
#pragma unroll
        for (int r = 0; r < 4; r++) {
            const int row = row0 + quad * 4 + r;
            if (row < n) {
                const float o = acc[nt][r] + bias;
                out[(size_t)row * 128 + col] = o;
                s += o;
                q += o * o;
            }
        }
        atomicAdd(&bs[col], s);
        atomicAdd(&bs[128 + col], q);
    }
    __syncthreads();
    atomicAdd(&stats[tid], bs[tid]);
}

// ====== fp32 linear layer-1 (K=32 -> 128), LDS-staged A/h, fused col-stats ======
__global__ __launch_bounds__(256) void linear1s_k(
    const float* __restrict__ agg, const float* __restrict__ h,
    const float* __restrict__ wl, const float* __restrict__ bl,
    const float* __restrict__ wr, float* __restrict__ out,
    float* __restrict__ stats, int n) {
    constexpr int DOUT = 128, CT = 32, RB = 32, LDW = 36;
    __shared__ float Ash[RB * LDW];   // 4.6 KB (reused as stats scratch)
    __shared__ float Hsh[RB * LDW];   // 4.6 KB
    const int tid = threadIdx.x;
    const int base = blockIdx.x * RB;
    {   // stage: thread = (row = tid>>3, chunk = tid&7); col = chunk*4
        const int sr = tid >> 3;
        const int col = (tid & 7) * 4;
        const int grow = min(base + sr, n - 1);
        *(float4*)(Ash + sr * LDW + col) = *(const float4*)(agg + (size_t)grow * 32 + col);
        *(float4*)(Hsh + sr * LDW + col) = *(const float4*)(h + (size_t)grow * 32 + col);
    }
    __syncthreads();
    const int ct = tid % CT;
    const int rt = tid / CT;
    const int col = ct * 4;
    const int row0 = base + rt * 4;
    float4 acc[4] = {};
#pragma unroll 2
    for (int k0 = 0; k0 < 32; k0 += 4) {
        float4 wlv[4], wrv[4];
#pragma unroll
        for (int j = 0; j < 4; j++) {
            wlv[j] = *(const float4*)(wl + (size_t)(k0 + j) * DOUT + col);
            wrv[j] = *(const float4*)(wr + (size_t)(k0 + j) * DOUT + col);
        }
#pragma unroll
        for (int r = 0; r < 4; r++) {
            const float4 av = *(const float4*)(Ash + (rt * 4 + r) * LDW + k0);
            const float4 hv = *(const float4*)(Hsh + (rt * 4 + r) * LDW + k0);
#pragma unroll
            for (int j = 0; j < 4; j++) {
                const float aa = j == 0 ? av.x : j == 1 ? av.y : j == 2 ? av.z : av.w;
                const float bb = j == 0 ? hv.x : j == 1 ? hv.y : j == 2 ? hv.z : hv.w;
                acc[r].x += aa * wlv[j].x + bb * wrv[j].x;
                acc[r].y += aa * wlv[j].y + bb * wrv[j].y;
                acc[r].z += aa * wlv[j].z + bb * wrv[j].z;
                acc[r].w += aa * wlv[j].w + bb * wrv[j].w;
            }
        }
    }
    const float4 bv = *(const float4*)(bl + col);
    float cs[4] = {}, cq[4] = {};
#pragma unroll
    for (int r = 0; r < 4; r++) {
        if (row0 + r < n) {
            float4 o = acc[r];
            o.x += bv.x; o.y += bv.y; o.z += bv.z; o.w += bv.w;
            *(float4*)(out + (size_t)(row0 + r) * DOUT + col) = o;
            cs[0] += o.x; cq[0] += o.x * o.x;
            cs[1] += o.y; cq[1] += o.y * o.y;
            cs[2] += o.z; cq[2] += o.z * o.z;
            cs[3] += o.w; cq[3] += o.w * o.w;
        }
    }
    // block-level column reduce (8 row-threads per column group) -> atomic stats
    __syncthreads();
#pragma unroll
    for (int j = 0; j < 4; j++) Ash[tid * 4 + j] = cs[j];
    __syncthreads();
    if (tid < CT) {
#pragma unroll
        for (int j = 0; j < 4; j++) {
            float s = 0.f;
#pragma unroll
            for (int k = 0; k < 8; k++) s += Ash[(tid + k * CT) * 4 + j];
            atomicAdd(&stats[tid * 4 + j], s);
        }
    }
    __syncthreads();
#pragma unroll
    for (int j = 0; j < 4; j++) Ash[tid * 4 + j] = cq[j];
    __syncthreads();
    if (tid < CT) {
#pragma unroll
        for (int j = 0; j < 4; j++) {
            float s = 0.f;
#pragma unroll
            for (int k = 0; k < 8; k++) s += Ash[(tid + k * CT) * 4 + j];
            atomicAdd(&stats[128 + tid * 4 + j], s);
        }
    }
}

// ====== fp32 linear (layer-2, K=128 -> 64), LDS-staged A/h ======
__global__ __launch_bounds__(256) void linear2_k(
    const float* __restrict__ agg, const float* __restrict__ h,
    const float* __restrict__ coef, const float* __restrict__ wl,
    const float* __restrict__ bl, const float* __restrict__ wr,
    float* __restrict__ out, float* __restrict__ stats, int n) {
    constexpr int DIN = 128, DOUT = 64, CT = 16, RB = 64, LDW = 132;
    __shared__ float Ash[RB * LDW];
    __shared__ float Hsh[RB * LDW];
    const int tid = threadIdx.x;
    const int base = blockIdx.x * RB;
    {
        const int sr = tid >> 2;
        const int sc = tid & 3;
        const int grow = min(base + sr, n - 1);
        const float* ar = agg + (size_t)grow * DIN;
        const float* hr = h + (size_t)grow * DIN;
#pragma unroll
        for (int c = 0; c < 8; c++) {
            const int col = (sc + c * 4) * 4;
            const float4 av = *(const float4*)(ar + col);
            float4 hv = *(const float4*)(hr + col);
            const float4 ca = *(const float4*)(coef + col);
            const float4 cb = *(const float4*)(coef + DIN + col);
            hv.x = trf(hv.x, ca.x, cb.x); hv.y = trf(hv.y, ca.y, cb.y);
            hv.z = trf(hv.z, ca.z, cb.z); hv.w = trf(hv.w, ca.w, cb.w);
            *(float4*)(Ash + sr * LDW + col) = av;
            *(float4*)(Hsh + sr * LDW + col) = hv;
        }
    }
    __syncthreads();
    const int ct = tid % CT;
    const int rt = tid / CT;
    const int col = ct * 4;
    const int row0 = base + rt * 4;
    float4 acc[4] = {};
#pragma unroll 2
    for (int k0 = 0; k0 < DIN; k0 += 4) {
        float4 wlv[4], wrv[4];
#pragma unroll
        for (int j = 0; j < 4; j++) {
            wlv[j] = *(const float4*)(wl + (size_t)(k0 + j) * DOUT + col);
            wrv[j] = *(const float4*)(wr + (size_t)(k0 + j) * DOUT + col);
        }
#pragma unroll
        for (int r = 0; r < 4; r++) {
            const float4 av = *(const float4*)(Ash + (rt * 4 + r) * LDW + k0);
            const float4 hv = *(const float4*)(Hsh + (rt * 4 + r) * LDW + k0);
#pragma unroll
            for (int j = 0; j < 4; j++) {
                const float aa = j == 0 ? av.x : j == 1 ? av.y : j == 2 ? av.z : av.w;
                const float bb = j == 0 ? hv.x : j == 1 ? hv.y : j == 2 ? hv.z : hv.w;
                acc[r].x += aa * wlv[j].x + bb * wrv[j].x;
                acc[r].y += aa * wlv[j].y + bb * wrv[j].y;
                acc[r].z += aa * wlv[j].z + bb * wrv[j].z;
                acc[r].w += aa * wlv[j].w + bb * wrv[j].w;
            }
        }
    }
    const float4 bv = *(const float4*)(bl + col);
    float cs[4] = {}, cq[4] = {};
#pragma unroll
    for (int r = 0; r < 4; r++) {
        if (row0 + r < n) {
            float4 o = acc[r];
            o.x += bv.x; o.y += bv.y; o.z += bv.z; o.w += bv.w;
            *(float4*)(out + (size_t)(row0 + r) * DOUT + col) = o;
            cs[0] += o.x; cq[0] += o.x * o.x;
            cs[1] += o.y; cq[1] += o.y * o.y;
            cs[2] += o.z; cq[2] += o.z * o.z;
            cs[3] += o.w; cq[3] += o.w * o.w;
        }
    }
    __syncthreads();
#pragma unroll
    for (int j = 0; j < 4; j++) Ash[tid * 4 + j] = cs[j];
    __syncthreads();
    if (tid < CT) {
#pragma unroll
        for (int j = 0; j < 4; j++) {
            float s = 0.f;
#pragma unroll
            for (int k = 0; k < 16; k++) s += Ash[(tid + k * CT) * 4 + j];
            atomicAdd(&stats[tid * 4 + j], s);
        }
    }
    __syncthreads();
#pragma unroll
    for (int j = 0; j < 4; j++) Ash[tid * 4 + j] = cq[j];
    __syncthreads();
    if (tid < CT) {
#pragma unroll
        for (int j = 0; j < 4; j++) {
            float s = 0.f;
#pragma unroll
            for (int k = 0; k < 16; k++) s += Ash[(tid + k * CT) * 4 + j];
            atomicAdd(&stats[64 + tid * 4 + j], s);
        }
    }
}

// ====== sh1 linear: concat([x(32), rm(3)]) -> 128, LDS-staged, fused rm-gather ======
__global__ __launch_bounds__(256) void linear_shs_k(
    const float* __restrict__ aggx, const float* __restrict__ x,
    const float* __restrict__ rmb, const int* __restrict__ ptr,
    const int* __restrict__ csr,
    const float* __restrict__ wl, const float* __restrict__ bl,
    const float* __restrict__ wr, float* __restrict__ out,
    float* __restrict__ stats, int n) {
    constexpr int DOUT = 128, CT = 32, RB = 32, LDW = 36;
    __shared__ float Ash[RB * LDW];
    __shared__ float Hsh[RB * LDW];
    __shared__ float Rsh[RB * 4], Msh[RB * 4];
    const int tid = threadIdx.x;
    const int base = blockIdx.x * RB;
    {
        const int sr = tid >> 3;
        const int col = (tid & 7) * 4;
        const int grow = min(base + sr, n - 1);
        *(float4*)(Ash + sr * LDW + col) = *(const float4*)(aggx + (size_t)grow * 32 + col);
        *(float4*)(Hsh + sr * LDW + col) = *(const float4*)(x + (size_t)grow * 32 + col);
        // fused gather of min over neighbors' rmb rows
        const int sub = tid & 7;
        const int e0 = ptr[grow];
        const int end2 = ptr[grow + 1];
        float q0 = FLTMAX, q1 = FLTMAX, q2 = FLTMAX;
        for (int e = e0 + sub; e < end2; e += 8) {
            const float* rr = rmb + (size_t)csr[e] * 3;
            q0 = fminf(q0, rr[0]);
            q1 = fminf(q1, rr[1]);
            q2 = fminf(q2, rr[2]);
        }
#pragma unroll
        for (int off = 1; off < 8; off <<= 1) {
            q0 = fminf(q0, __shfl_xor(q0, off));
            q1 = fminf(q1, __shfl_xor(q1, off));
            q2 = fminf(q2, __shfl_xor(q2, off));
        }
        if (sub == 0) {
            const bool em = (e0 == end2);
            Rsh[sr * 4 + 0] = em ? 0.f : q0;
            Rsh[sr * 4 + 1] = em ? 0.f : q1;
            Rsh[sr * 4 + 2] = em ? 0.f : q2;
            Msh[sr * 4 + 0] = rmb[(size_t)grow * 3 + 0];
            Msh[sr * 4 + 1] = rmb[(size_t)grow * 3 + 1];
            Msh[sr * 4 + 2] = rmb[(size_t)grow * 3 + 2];
        }
    }
    __syncthreads();
    const int ct = tid % CT;
    const int rt = tid / CT;
    const int col = ct * 4;
    const int row0 = base + rt * 4;
    float4 acc[4] = {};
#pragma unroll 2
    for (int k0 = 0; k0 < 32; k0 += 4) {
        float4 wlv[4], wrv[4];
#pragma unroll
        for (int j = 0; j < 4; j++) {
            wlv[j] = *(const float4*)(wl + (size_t)(k0 + j) * DOUT + col);
            wrv[j] = *(const float4*)(wr + (size_t)(k0 + j) * DOUT + col);
        }
#pragma unroll
        for (int r = 0; r < 4; r++) {
            const float4 av = *(const float4*)(Ash + (rt * 4 + r) * LDW + k0);
            const float4 hv = *(const float4*)(Hsh + (rt * 4 + r) * LDW + k0);
#pragma unroll
            for (int j = 0; j < 4; j++) {
                const float aa = j == 0 ? av.x : j == 1 ? av.y : j == 2 ? av.z : av.w;
                const float bb = j == 0 ? hv.x : j == 1 ? hv.y : j == 2 ? hv.z : hv.w;
                acc[r].x += aa * wlv[j].x + bb * wrv[j].x;
                acc[r].y += aa * wlv[j].y + bb * wrv[j].y;
                acc[r].z += aa * wlv[j].z + bb * wrv[j].z;
                acc[r].w += aa * wlv[j].w + bb * wrv[j].w;
            }
        }
    }
#pragma unroll
    for (int k = 0; k < 3; k++) {
        const float4 wlv = *(const float4*)(wl + (size_t)(32 + k) * DOUT + col);
        const float4 wrv = *(const float4*)(wr + (size_t)(32 + k) * DOUT + col);
#pragma unroll
        for (int r = 0; r < 4; r++) {
            const float a = Rsh[(rt * 4 + r) * 4 + k];
            const float b = Msh[(rt * 4 + r) * 4 + k];
            acc[r].x += a * wlv.x + b * wrv.x;
            acc[r].y += a * wlv.y + b * wrv.y;
            acc[r].z += a * wlv.z + b * wrv.z;
            acc[r].w += a * wlv.w + b * wrv.w;
        }
    }
    const float4 bv = *(const float4*)(bl + col);
    float cs[4] = {}, cq[4] = {};
#pragma unroll
    for (int r = 0; r < 4; r++) {
        if (row0 + r < n) {
            float4 o = acc[r];
            o.x += bv.x; o.y += bv.y; o.z += bv.z; o.w += bv.w;
            *(float4*)(out + (size_t)(row0 + r) * DOUT + col) = o;
            cs[0] += o.x; cq[0] += o.x * o.x;
            cs[1] += o.y; cq[1] += o.y * o.y;
            cs[2] += o.z; cq[2] += o.z * o.z;
            cs[3] += o.w; cq[3] += o.w * o.w;
        }
    }
    __syncthreads();
#pragma unroll
    for (int j = 0; j < 4; j++) Ash[tid * 4 + j] = cs[j];
    __syncthreads();
    if (tid < CT) {
#pragma unroll
        for (int j = 0; j < 4; j++) {
            float s = 0.f;
#pragma unroll
            for (int k = 0; k < 8; k++) s += Ash[(tid + k * CT) * 4 + j];
            atomicAdd(&stats[tid * 4 + j], s);
        }
    }
    __syncthreads();
#pragma unroll
    for (int j = 0; j < 4; j++) Ash[tid * 4 + j] = cq[j];
    __syncthreads();
    if (tid < CT) {
#pragma unroll
        for (int j = 0; j < 4; j++) {
            float s = 0.f;
#pragma unroll
            for (int k = 0; k < 8; k++) s += Ash[(tid + k * CT) * 4 + j];
            atomicAdd(&stats[128 + tid * 4 + j], s);
        }
    }
}

// ====== rm head fused: gather(h2,D=64) + 64->3 linear + log_softmax + labels ======
// gather uses sign-folded min; BN coef inlined from stats2.
__global__ __launch_bounds__(256) void rm_fused_k(
    const float* __restrict__ h2, const float* __restrict__ stats,
    const float* __restrict__ g, const float* __restrict__ be,
    const int* __restrict__ ptr, const int* __restrict__ csr,
    const float* __restrict__ wl, const float* __restrict__ bl,
    const float* __restrict__ wr, float* __restrict__ rmb,
    float* __restrict__ ls_out, float* __restrict__ lab, float invN, int n) {
    const int lane = threadIdx.x & 63;
    const int node = (blockIdx.x * 256 + threadIdx.x) >> 6;
    if (node >= n) return;
    float a, b;
    bncoef(stats[lane], stats[64 + lane], g[lane], be[lane], invN, a, b);
    const u32 sm = (a < 0.f) ? 0x80000000u : 0u;
    int e = ptr[node];
    const int end = ptr[node + 1];
    const bool empty = (e == end);
    float m = FLTMAX;
    for (; e + 15 < end; e += 16) {
        int s[16];
#pragma unroll
        for (int j = 0; j < 16; j++) s[j] = csr[e + j];
        float v[16];
#pragma unroll
        for (int j = 0; j < 16; j++) v[j] = h2[(size_t)s[j] * 64 + lane];
#pragma unroll
        for (int j = 0; j < 16; j++) m = sfmin(m, v[j], sm);
    }
    for (; e + 3 < end; e += 4) {
        int s[4];
#pragma unroll
        for (int j = 0; j < 4; j++) s[j] = csr[e + j];
        float v[4];
#pragma unroll
        for (int j = 0; j < 4; j++) v[j] = h2[(size_t)s[j] * 64 + lane];
#pragma unroll
        for (int j = 0; j < 4; j++) m = sfmin(m, v[j], sm);
    }
    for (; e < end; e++) m = sfmin(m, h2[(size_t)csr[e] * 64 + lane], sm);
    const float mv = empty ? 0.f : trf(sdec(m, sm), a, b);
    const float hv = trf(h2[(size_t)node * 64 + lane], a, b);
    float c0 = mv * wl[lane * 3 + 0] + hv * wr[lane * 3 + 0];
    float c1 = mv * wl[lane * 3 + 1] + hv * wr[lane * 3 + 1];
    float c2 = mv * wl[lane * 3 + 2] + hv * wr[lane * 3 + 2];
#pragma unroll
    for (int off = 1; off < 64; off <<= 1) {
        c0 += __shfl_xor(c0, off);
        c1 += __shfl_xor(c1, off);
        c2 += __shfl_xor(c2, off);
    }
    const float r0 = c0 + bl[0], r1 = c1 + bl[1], r2 = c2 + bl[2];
    if (lane < 3) {
        const float r = lane == 0 ? r0 : lane == 1 ? r1 : r2;
        rmb[(size_t)node * 3 + lane] = r;
        const float mx = fmaxf(r0, fmaxf(r1, r2));
        const float lse = mx + logf(expf(r0 - mx) + expf(r1 - mx) + expf(r2 - mx));
        ls_out[(size_t)node * 3 + lane] = r - lse;
        if (lane == 0) lab[node] = (r2 > r0 && r2 > r1) ? 1.f : 0.f;
    }
}

// ====== final heads: wave-per-node, coalesced + shuffle reduce; coef inlined ======
__global__ __launch_bounds__(256) void final_k(
    const float* __restrict__ rtmd, const float* __restrict__ stats,
    const float* __restrict__ gR, const float* __restrict__ bR,
    const float* __restrict__ gM, const float* __restrict__ bM,
    const float* __restrict__ rtw, const float* __restrict__ rtb,
    const float* __restrict__ mdw, const float* __restrict__ mdb,
    const float* __restrict__ lab, float* __restrict__ out_rt,
    float* __restrict__ out_md, float invN, int n) {
    const int lane = threadIdx.x & 63;
    const int node = (blockIdx.x * 256 + threadIdx.x) >> 6;
    if (node >= n) return;
    float aR, bRc, aM, bMc;
    bncoef(stats[lane], stats[128 + lane], gR[lane], bR[lane], invN, aR, bRc);
    bncoef(stats[64 + lane], stats[192 + lane], gM[lane], bM[lane], invN, aM, bMc);
    const float* rr = rtmd + (size_t)node * 128;
    float a = trf(rr[lane], aR, bRc) * rtw[lane];
    float b = trf(rr[64 + lane], aM, bMc) * mdw[lane];
#pragma unroll
    for (int off = 1; off < 64; off <<= 1) {
        a += __shfl_xor(a, off);
        b += __shfl_xor(b, off);
    }
    if (lane == 0) {
        const float l = lab[node];
        out_rt[node] = (a + rtb[0]) * l;
        out_md[node] = (b + mdb[0]) * l;
    }
}

extern "C" void kernel_launch(void* const* d_in, const int* in_sizes, int n_in,
                              void* d_out, int out_size, void* d_ws, size_t ws_size,
                              hipStream_t stream) {
    const float* x = (const float*)d_in[0];
    const int* ei = (const int*)d_in[1];
    const int E = in_sizes[1] / 2;
    const int n = in_sizes[0] / 32;
    const int* src = ei;
    const int* dst = ei + E;

    const float* rm1_wl = (const float*)d_in[2];
    const float* rm1_bl = (const float*)d_in[3];
    const float* rm1_wr = (const float*)d_in[4];
    const float* rmn1_g = (const float*)d_in[5];
    const float* rmn1_b = (const float*)d_in[6];
    const float* rm2_wl = (const float*)d_in[7];
    const float* rm2_bl = (const float*)d_in[8];
    const float* rm2_wr = (const float*)d_in[9];
    const float* rmn2_g = (const float*)d_in[10];
    const float* rmn2_b = (const float*)d_in[11];
    const float* rm4_wl = (const float*)d_in[12];
    const float* rm4_bl = (const float*)d_in[13];
    const float* rm4_wr = (const float*)d_in[14];
    const float* sh1_wl = (const float*)d_in[15];
    const float* sh1_bl = (const float*)d_in[16];
    const float* sh1_wr = (const float*)d_in[17];
    const float* shn1_g = (const float*)d_in[18];
    const float* shn1_b = (const float*)d_in[19];
    const float* rt1_wl = (const float*)d_in[20];
    const float* rt1_bl = (const float*)d_in[21];
    const float* rt1_wr = (const float*)d_in[22];
    const float* rtn1_g = (const float*)d_in[23];
    const float* rtn1_b = (const float*)d_in[24];
    const float* rt3_w = (const float*)d_in[25];
    const float* rt3_b = (const float*)d_in[26];
    const float* md1_wl = (const float*)d_in[27];
    const float* md1_bl = (const float*)d_in[28];
    const float* md1_wr = (const float*)d_in[29];
    const float* mdn1_g = (const float*)d_in[30];
    const float* mdn1_b = (const float*)d_in[31];
    const float* md3_w = (const float*)d_in[32];
    const float* md3_b = (const float*)d_in[33];

    // workspace layout; shbuf serves as fp32 aggB (layer 2), then bf16 Acat (dual)
    char* w = (char*)d_ws;
    float* aggX  = (float*)w; w += (size_t)n * 32 * 4;
    float* h1    = (float*)w; w += (size_t)n * 128 * 4;   // h1 raw, later h3 raw
    char*  shbuf = w;         w += (size_t)n * 512;       // aggB fp32 [n][128] | Acat bf16 [n][256]
    float* h2rt  = (float*)w; w += (size_t)n * 128 * 4;   // h2 [n][64], later rtmd [n][128]
    float* rmb   = (float*)w; w += (size_t)n * 3 * 4;
    float* aggR  = (float*)w; w += (size_t)n * 3 * 4;     // (unused, kept for layout)
    float* lab   = (float*)w; w += (size_t)n * 4;
    float* stats = (float*)w; w += 1024 * 4;
    float* coef  = (float*)w; w += 1024 * 4;
    u16*   WTD   = (u16*)w;   w += (size_t)128 * 256 * 2;
    int* ptr  = (int*)w; w += (size_t)(n + 1) * 4;
    int* pos  = (int*)w; w += (size_t)n * 4;
    int* bsum = (int*)w; w += 1024 * 4;
    int* csr  = (int*)w; w += (size_t)E * 4;

    float* aggB = (float*)shbuf;
    u16*   Acat = (u16*)shbuf;
    float* h2 = h2rt;
    float* rtmd = h2rt;
    float* stats1 = stats, *stats2 = stats + 256, *statsSh = stats + 512, *statsD = stats + 768;
    float* coef1 = coef;   // exported by gather_min128 block 0, read by linear2

    float* out = (float*)d_out;
    float* out_ls = out;
    float* out_rt = out + (size_t)3 * n;
    float* out_md = out + (size_t)4 * n;

    const float invN = 1.f / (float)n;
    auto cdiv = [](int a, int b) { return (a + b - 1) / b; };
    const int nb = cdiv(n, 256);
    const int nb32 = cdiv(n, 32);
    const int nb64 = cdiv(n, 64);
    const int lo_step = cdiv(n, 8);

    hipMemsetAsync(stats, 0, 1024 * 4, stream);
    hipMemsetAsync(pos, 0, (size_t)n * 4, stream);

    // ---- CSR build (XCD-partitioned hist + fill) + dual-weight prep
    hist_part_k<<<cdiv(E, 256) * 8, 256, 0, stream>>>(dst, pos, E, lo_step);
    wprep_dual_k<<<128, 256, 0, stream>>>(rt1_wl, rt1_wr, md1_wl, md1_wr, WTD);
    scan_block_k<<<nb, 256, 0, stream>>>(pos, ptr, bsum, n);
    scan_add_k<<<nb, 256, 0, stream>>>(ptr, pos, bsum, n, E);
    csr_fill_part_k<<<cdiv(E, 256) * 8, 256, 0, stream>>>(src, dst, pos, csr, E, lo_step);

    // ---- layer 1 (fp32): agg(x) -> linear (stats direct-atomic) -> h1
    gather_min32_k<<<cdiv(n, 8), 256, 0, stream>>>(x, ptr, csr, aggX, n);
    linear1s_k<<<nb32, 256, 0, stream>>>(aggX, x, rm1_wl, rm1_bl, rm1_wr, h1, stats1, n);

    // ---- layer 2 (fp32, label-critical): gather(bnrelu(h1)) [coef1 inline+export]
    gather_min128_k<<<cdiv(n, 4), 256, 0, stream>>>(h1, ptr, csr, stats1, rmn1_g, rmn1_b,
                                                    coef1, aggB, invN, n);
    linear2_k<<<nb64, 256, 0, stream>>>(aggB, h1, coef1, rm2_wl, rm2_bl, rm2_wr, h2, stats2, n);

    // ---- rm head (fp32): fused gather + linear + log_softmax + labels [coef2 inline]
    rm_fused_k<<<cdiv(n, 4), 256, 0, stream>>>(h2, stats2, rmn2_g, rmn2_b, ptr, csr,
                                               rm4_wl, rm4_bl, rm4_wr, rmb, out_ls, lab, invN, n);

    // ---- sh1 (fp32): linear concat([x,rm]) with fused rm-gather -> h3 (h1 buf)
    linear_shs_k<<<nb32, 256, 0, stream>>>(aggX, x, rmb, ptr, csr,
                                           sh1_wl, sh1_bl, sh1_wr, h1, statsSh, n);

    // ---- dual rt/md (bf16 MFMA): convert [coefSh inline] -> gather -> GEMM
    convert_k<<<cdiv(n * 32, 256), 256, 0, stream>>>(h1, statsSh, shn1_g, shn1_b, Acat, invN, n);
    gather_bf_k<<<cdiv(n, 8), 256, 0, stream>>>(Acat, ptr, csr, n);
    gemm_bf_k<<<nb64, 256, 0, stream>>>(Acat, WTD, rt1_bl, md1_bl, rtmd, statsD, n);

    // ---- final heads [coefRt/Md inline]
    final_k<<<cdiv(n, 4), 256, 0, stream>>>(rtmd, statsD, rtn1_g, rtn1_b, mdn1_g, mdn1_b,
                                            rt3_w, rt3_b, md3_w, md3_b, lab,
                                            out_rt, out_md, invN, n);
}

// Round 7
// 859.325 us; speedup vs baseline: 1.7374x; 1.7374x over previous
//
#include <hip/hip_runtime.h>

#define FLTMAX 3.402823466e+38f
#define DEV __device__ __forceinline__

typedef unsigned short u16;
typedef unsigned int u32;
typedef __bf16 bf16_t;
typedef bf16_t bf16x8 __attribute__((ext_vector_type(8)));
typedef float f32x4 __attribute__((ext_vector_type(4)));

union U16x8 { uint4 u; bf16x8 b; };

DEV float trf(float v, float a, float b) { return fmaxf(fmaf(v, a, b), 0.f); }

// sign-folded min helpers: track min of (v ^ sm); sm=0x80000000 turns it into max-tracking
DEV float sfmin(float m, float v, u32 sm) {
    return fminf(m, __uint_as_float(__float_as_uint(v) ^ sm));
}
DEV float sdec(float m, u32 sm) { return __uint_as_float(__float_as_uint(m) ^ sm); }

// round-to-nearest-even fp32 -> bf16 bits (finite inputs)
DEV u16 f2bf(float f) {
    u32 u = __float_as_uint(f);
    return (u16)((u + 0x7FFFu + ((u >> 16) & 1u)) >> 16);
}

// BN coef from stats: a = rsqrt(var+eps)*g, b = beta - mu*a
DEV void bncoef(float s, float s2, float g, float be, float invN, float& a, float& b) {
    const float mu = s * invN;
    const float var = s2 * invN - mu * mu;
    a = rsqrtf(var + 1e-5f) * g;
    b = be - mu * a;
}

// ================= CSR build =================
// XCD-partitioned histogram: same dst-range partition as csr_fill (atomics stay XCD-local)
__global__ __launch_bounds__(256) void hist_part_k(const int* __restrict__ dst,
                                                   int* __restrict__ deg, int E, int lo_step) {
    const int part = blockIdx.x & 7;
    const int e = (blockIdx.x >> 3) * 256 + threadIdx.x;
    if (e >= E) return;
    const int d = dst[e];
    const int lo = part * lo_step;
    const int hi = lo + lo_step;
    if (d < lo || d >= hi) return;
    atomicAdd(&deg[d], 1);
}

__global__ __launch_bounds__(256) void scan_block_k(const int* __restrict__ deg,
                                                    int* __restrict__ ptr,
                                                    int* __restrict__ bsum, int n) {
    __shared__ int ls[256];
    int i = blockIdx.x * 256 + threadIdx.x;
    int v = (i < n) ? deg[i] : 0;
    ls[threadIdx.x] = v;
    __syncthreads();
#pragma unroll
    for (int off = 1; off < 256; off <<= 1) {
        int a = (threadIdx.x >= off) ? ls[threadIdx.x - off] : 0;
        __syncthreads();
        ls[threadIdx.x] += a;
        __syncthreads();
    }
    if (i < n) ptr[i] = ls[threadIdx.x] - v;
    if (threadIdx.x == 255) bsum[blockIdx.x] = ls[255];
}

// scan_add with inline prefix over raw bsum
__global__ __launch_bounds__(256) void scan_add_k(int* __restrict__ ptr,
                                                  int* __restrict__ pos,
                                                  const int* __restrict__ bsum,
                                                  int n, int E) {
    __shared__ int shw[4];
    const int tid = threadIdx.x;
    int part = 0;
    for (int k = tid; k < blockIdx.x; k += 256) part += bsum[k];
#pragma unroll
    for (int off = 1; off < 64; off <<= 1) part += __shfl_xor(part, off);
    if ((tid & 63) == 0) shw[tid >> 6] = part;
    __syncthreads();
    const int boff = shw[0] + shw[1] + shw[2] + shw[3];
    const int i = blockIdx.x * 256 + tid;
    if (i == 0) ptr[n] = E;
    if (i < n) {
        int p = ptr[i] + boff;
        ptr[i] = p;
        pos[i] = p;
    }
}

// XCD-partitioned fill: partition = blockIdx & 7
__global__ __launch_bounds__(256) void csr_fill_part_k(
    const int* __restrict__ src, const int* __restrict__ dst,
    int* __restrict__ pos, int* __restrict__ csr, int E, int lo_step) {
    const int part = blockIdx.x & 7;
    const int e = (blockIdx.x >> 3) * 256 + threadIdx.x;
    if (e >= E) return;
    const int d = dst[e];
    const int lo = part * lo_step;
    const int hi = lo + lo_step;
    if (d < lo || d >= hi) return;
    const int p = atomicAdd(&pos[d], 1);
    csr[p] = src[e];
}

// ====== fp32 gather min (layer-1 x, D=32) ======
__global__ __launch_bounds__(256) void gather_min32_k(
    const float* __restrict__ feat, const int* __restrict__ ptr,
    const int* __restrict__ csr, float* __restrict__ agg, int n) {
    const int lane = threadIdx.x & 63;
    const int wave = (blockIdx.x * 256 + threadIdx.x) >> 6;
    const int node = wave * 2 + (lane >> 5);
    if (node >= n) return;
    const int fl = lane & 31;
    int e = ptr[node];
    const int end = ptr[node + 1];
    const bool empty = (e == end);
    float m = FLTMAX;
    for (; e + 7 < end; e += 8) {
        int s[8];
#pragma unroll
        for (int j = 0; j < 8; j++) s[j] = csr[e + j];
        float v[8];
#pragma unroll
        for (int j = 0; j < 8; j++) v[j] = feat[(size_t)s[j] * 32 + fl];
#pragma unroll
        for (int j = 0; j < 8; j++) m = fminf(m, v[j]);
    }
    for (; e < end; e++) m = fminf(m, feat[(size_t)csr[e] * 32 + fl]);
    agg[(size_t)node * 32 + fl] = empty ? 0.f : m;
}

// ====== fp32 gather min D=128, fused BN+ReLU (sign-folded) ======
// 1 node per 64-lane wave, float2/lane. Inline coef from stats; block0 exports coef1.
__global__ __launch_bounds__(256) void gather_min128_k(
    const float* __restrict__ feat, const int* __restrict__ ptr,
    const int* __restrict__ csr, const float* __restrict__ stats,
    const float* __restrict__ g, const float* __restrict__ be,
    float* __restrict__ coef_out, float* __restrict__ agg, float invN, int n) {
    const int lane = threadIdx.x & 63;
    const int node = (blockIdx.x * 256 + threadIdx.x) >> 6;
    if (node >= n) return;
    const int fl = lane * 2;
    float ca0, cb0, ca1, cb1;
    bncoef(stats[fl], stats[128 + fl], g[fl], be[fl], invN, ca0, cb0);
    bncoef(stats[fl + 1], stats[129 + fl], g[fl + 1], be[fl + 1], invN, ca1, cb1);
    if (blockIdx.x == 0 && threadIdx.x < 64) {   // export for linear2
        coef_out[fl] = ca0; coef_out[fl + 1] = ca1;
        coef_out[128 + fl] = cb0; coef_out[129 + fl] = cb1;
    }
    const u32 sm0 = (ca0 < 0.f) ? 0x80000000u : 0u;
    const u32 sm1 = (ca1 < 0.f) ? 0x80000000u : 0u;
    int e = ptr[node];
    const int end = ptr[node + 1];
    const bool empty = (e == end);
    float m0 = FLTMAX, m1 = FLTMAX;
    for (; e + 7 < end; e += 8) {
        int s[8];
#pragma unroll
        for (int j = 0; j < 8; j++) s[j] = csr[e + j];
        float2 v[8];
#pragma unroll
        for (int j = 0; j < 8; j++) v[j] = *(const float2*)(feat + (size_t)s[j] * 128 + fl);
#pragma unroll
        for (int j = 0; j < 8; j++) {
            m0 = sfmin(m0, v[j].x, sm0);
            m1 = sfmin(m1, v[j].y, sm1);
        }
    }
    for (; e + 3 < end; e += 4) {
        int s[4];
#pragma unroll
        for (int j = 0; j < 4; j++) s[j] = csr[e + j];
        float2 v[4];
#pragma unroll
        for (int j = 0; j < 4; j++) v[j] = *(const float2*)(feat + (size_t)s[j] * 128 + fl);
#pragma unroll
        for (int j = 0; j < 4; j++) {
            m0 = sfmin(m0, v[j].x, sm0);
            m1 = sfmin(m1, v[j].y, sm1);
        }
    }
    for (; e < end; e++) {
        const float2 v = *(const float2*)(feat + (size_t)csr[e] * 128 + fl);
        m0 = sfmin(m0, v.x, sm0);
        m1 = sfmin(m1, v.y, sm1);
    }
    float2 o;
    o.x = empty ? 0.f : trf(sdec(m0, sm0), ca0, cb0);
    o.y = empty ? 0.f : trf(sdec(m1, sm1), ca1, cb1);
    *(float2*)(agg + (size_t)node * 128 + fl) = o;
}

// ====== bf16 gather min over A_cat right half -> left half ======
// 2 nodes/wave: 32 lanes x uint2 (4 bf16) per neighbor row.
__global__ __launch_bounds__(256) void gather_bf_k(
    u16* __restrict__ Acat, const int* __restrict__ ptr,
    const int* __restrict__ csr, int n) {
    const int lane = threadIdx.x & 63;
    const int wave = (blockIdx.x * 256 + threadIdx.x) >> 6;
    const int node = wave * 2 + (lane >> 5);
    if (node >= n) return;
    const int fl = (lane & 31) * 4;   // u16 index; 32 lanes x 4 = 128 cols
    int e = ptr[node];
    const int end = ptr[node + 1];
    uint2 outv = {0u, 0u};
    if (e != end) {
        float m0 = FLTMAX, m1 = FLTMAX, m2 = FLTMAX, m3 = FLTMAX;
        for (; e + 7 < end; e += 8) {
            int s[8];
#pragma unroll
            for (int j = 0; j < 8; j++) s[j] = csr[e + j];
            uint2 v[8];
#pragma unroll
            for (int j = 0; j < 8; j++) v[j] = *(const uint2*)(Acat + (size_t)s[j] * 256 + 128 + fl);
#pragma unroll
            for (int j = 0; j < 8; j++) {
                m0 = fminf(m0, __uint_as_float(v[j].x << 16));
                m1 = fminf(m1, __uint_as_float(v[j].x & 0xffff0000u));
                m2 = fminf(m2, __uint_as_float(v[j].y << 16));
                m3 = fminf(m3, __uint_as_float(v[j].y & 0xffff0000u));
            }
        }
        for (; e < end; e++) {
            const uint2 v = *(const uint2*)(Acat + (size_t)csr[e] * 256 + 128 + fl);
            m0 = fminf(m0, __uint_as_float(v.x << 16));
            m1 = fminf(m1, __uint_as_float(v.x & 0xffff0000u));
            m2 = fminf(m2, __uint_as_float(v.y << 16));
            m3 = fminf(m3, __uint_as_float(v.y & 0xffff0000u));
        }
        outv.x = (__float_as_uint(m0) >> 16) | (__float_as_uint(m1) & 0xffff0000u);
        outv.y = (__float_as_uint(m2) >> 16) | (__float_as_uint(m3) & 0xffff0000u);
    }
    *(uint2*)(Acat + (size_t)node * 256 + fl) = outv;
}

// ====== convert bn_relu(h) (D=128) -> bf16 into A_cat right half (coef inlined) ======
__global__ __launch_bounds__(256) void convert_k(
    const float* __restrict__ h, const float* __restrict__ stats,
    const float* __restrict__ g, const float* __restrict__ be,
    u16* __restrict__ Acat, float invN, int n) {
    int t = blockIdx.x * 256 + threadIdx.x;
    int total = n * 32;
    if (t >= total) return;
    int i = t >> 5;
    int dq = (t & 31) * 4;
    const float4 s1 = *(const float4*)(stats + dq);
    const float4 s2 = *(const float4*)(stats + 128 + dq);
    const float4 gv = *(const float4*)(g + dq);
    const float4 ev = *(const float4*)(be + dq);
    float4 ca, cb;
    bncoef(s1.x, s2.x, gv.x, ev.x, invN, ca.x, cb.x);
    bncoef(s1.y, s2.y, gv.y, ev.y, invN, ca.y, cb.y);
    bncoef(s1.z, s2.z, gv.z, ev.z, invN, ca.z, cb.z);
    bncoef(s1.w, s2.w, gv.w, ev.w, invN, ca.w, cb.w);
    const float4 hv = *(const float4*)(h + (size_t)i * 128 + dq);
    ushort4 o;
    o.x = f2bf(trf(hv.x, ca.x, cb.x));
    o.y = f2bf(trf(hv.y, ca.y, cb.y));
    o.z = f2bf(trf(hv.z, ca.z, cb.z));
    o.w = f2bf(trf(hv.w, ca.w, cb.w));
    *(ushort4*)(Acat + (size_t)i * 256 + 128 + dq) = o;
}

// ====== weight prep (dual, one launch): WT row c: c<64 -> rt pair, else md pair ======
__global__ __launch_bounds__(256) void wprep_dual_k(
    const float* __restrict__ rwl, const float* __restrict__ rwr,
    const float* __restrict__ mwl, const float* __restrict__ mwr,
    u16* __restrict__ WT) {
    int t = blockIdx.x * 256 + threadIdx.x;   // 128*256 total
    int c = t >> 8;
    int k = t & 255;
    const float* wlp = (c < 64) ? rwl : mwl;
    const float* wrp = (c < 64) ? rwr : mwr;
    const int cc = c & 63;
    float v = (k < 128) ? wlp[k * 64 + cc] : wrp[(k - 128) * 64 + cc];
    WT[(size_t)c * 256 + k] = f2bf(v);
}

// ====== bf16 MFMA GEMM: out[n][128] = A_cat[n][256] @ W_cat[256][128] + bias ======
// fused per-block column stats -> bpart[blk][256] (s | s2)
__global__ __launch_bounds__(256) void gemm_bf_k(
    const u16* __restrict__ A, const u16* __restrict__ WT,
    const float* __restrict__ bl1, const float* __restrict__ bl2,
    float* __restrict__ out, float* __restrict__ bpart, int n) {
    constexpr int NT = 8;
    __shared__ float bs[256];
    const int tid = threadIdx.x;
    bs[tid] = 0.f;
    const int wave = tid >> 6, lane = tid & 63;
    const int quad = lane >> 4, l16 = lane & 15;
    const int row0 = blockIdx.x * 64 + wave * 16;
    const int rowA = min(row0 + l16, n - 1);
    const uint4* Arow = (const uint4*)(A + (size_t)rowA * 256) + quad;

    bf16x8 a[8];
#pragma unroll
    for (int kc = 0; kc < 8; kc++) {
        U16x8 u; u.u = Arow[kc * 4];
        a[kc] = u.b;
    }
    f32x4 acc[NT];
#pragma unroll
    for (int i = 0; i < NT; i++) acc[i] = (f32x4){0.f, 0.f, 0.f, 0.f};
#pragma unroll
    for (int nt = 0; nt < NT; nt++) {
        const uint4* Brow = (const uint4*)(WT + (size_t)(nt * 16 + l16) * 256) + quad;
#pragma unroll
        for (int kc = 0; kc < 8; kc++) {
            U16x8 u; u.u = Brow[kc * 4];
            acc[nt] = __builtin_amdgcn_mfma_f32_16x16x32_bf16(a[kc], u.b, acc[nt], 0, 0, 0);
        }
    }
    __syncthreads();   // bs[] zeroed by all waves before atomics below
#pragma unroll
    for (int nt = 0; nt < NT; nt++) {
        const int col = nt * 16 + l16;
        const float bias = (col < 64) ? bl1[col] : bl2[col - 64];
        float s = 0.f, q = 0.f;
#pragma unroll
        for (int r = 0; r < 4; r++) {
            const int row = row0 + quad * 4 + r;
            if (row < n) {
                const float o = acc[nt][r] + bias;
                out[(size_t)row * 128 + col] = o;
                s += o;
                q += o * o;
            }
        }
        atomicAdd(&bs[col], s);
        atomicAdd(&bs[128 + col], q);
    }
    __syncthreads();
    bpart[(size_t)blockIdx.x * 256 + tid] = bs[tid];
}

// ====== fp32 linear layer-1 (K=32 -> 128), LDS-staged A/h, fused col-stats ======
__global__ __launch_bounds__(256) void linear1s_k(
    const float* __restrict__ agg, const float* __restrict__ h,
    const float* __restrict__ wl, const float* __restrict__ bl,
    const float* __restrict__ wr, float* __restrict__ out,
    float* __restrict__ bpart, int n) {
    constexpr int DOUT = 128, CT = 32, RB = 32, LDW = 36;
    __shared__ float Ash[RB * LDW];   // 4.6 KB (reused as stats scratch)
    __shared__ float Hsh[RB * LDW];   // 4.6 KB
    const int tid = threadIdx.x;
    const int base = blockIdx.x * RB;
    {   // stage: thread = (row = tid>>3, chunk = tid&7); col = chunk*4
        const int sr = tid >> 3;
        const int col = (tid & 7) * 4;
        const int grow = min(base + sr, n - 1);
        *(float4*)(Ash + sr * LDW + col) = *(const float4*)(agg + (size_t)grow * 32 + col);
        *(float4*)(Hsh + sr * LDW + col) = *(const float4*)(h + (size_t)grow * 32 + col);
    }
    __syncthreads();
    const int ct = tid % CT;
    const int rt = tid / CT;
    const int col = ct * 4;
    const int row0 = base + rt * 4;
    float4 acc[4] = {};
#pragma unroll 2
    for (int k0 = 0; k0 < 32; k0 += 4) {
        float4 wlv[4], wrv[4];
#pragma unroll
        for (int j = 0; j < 4; j++) {
            wlv[j] = *(const float4*)(wl + (size_t)(k0 + j) * DOUT + col);
            wrv[j] = *(const float4*)(wr + (size_t)(k0 + j) * DOUT + col);
        }
#pragma unroll
        for (int r = 0; r < 4; r++) {
            const float4 av = *(const float4*)(Ash + (rt * 4 + r) * LDW + k0);
            const float4 hv = *(const float4*)(Hsh + (rt * 4 + r) * LDW + k0);
#pragma unroll
            for (int j = 0; j < 4; j++) {
                const float aa = j == 0 ? av.x : j == 1 ? av.y : j == 2 ? av.z : av.w;
                const float bb = j == 0 ? hv.x : j == 1 ? hv.y : j == 2 ? hv.z : hv.w;
                acc[r].x += aa * wlv[j].x + bb * wrv[j].x;
                acc[r].y += aa * wlv[j].y + bb * wrv[j].y;
                acc[r].z += aa * wlv[j].z + bb * wrv[j].z;
                acc[r].w += aa * wlv[j].w + bb * wrv[j].w;
            }
        }
    }
    const float4 bv = *(const float4*)(bl + col);
    float cs[4] = {}, cq[4] = {};
#pragma unroll
    for (int r = 0; r < 4; r++) {
        if (row0 + r < n) {
            float4 o = acc[r];
            o.x += bv.x; o.y += bv.y; o.z += bv.z; o.w += bv.w;
            *(float4*)(out + (size_t)(row0 + r) * DOUT + col) = o;
            cs[0] += o.x; cq[0] += o.x * o.x;
            cs[1] += o.y; cq[1] += o.y * o.y;
            cs[2] += o.z; cq[2] += o.z * o.z;
            cs[3] += o.w; cq[3] += o.w * o.w;
        }
    }
    // block-level column reduce (8 row-threads per column group) -> bpart
    __syncthreads();
#pragma unroll
    for (int j = 0; j < 4; j++) Ash[tid * 4 + j] = cs[j];
    __syncthreads();
    if (tid < CT) {
#pragma unroll
        for (int j = 0; j < 4; j++) {
            float s = 0.f;
#pragma unroll
            for (int k = 0; k < 8; k++) s += Ash[(tid + k * CT) * 4 + j];
            bpart[(size_t)blockIdx.x * 256 + tid * 4 + j] = s;
        }
    }
    __syncthreads();
#pragma unroll
    for (int j = 0; j < 4; j++) Ash[tid * 4 + j] = cq[j];
    __syncthreads();
    if (tid < CT) {
#pragma unroll
        for (int j = 0; j < 4; j++) {
            float s = 0.f;
#pragma unroll
            for (int k = 0; k < 8; k++) s += Ash[(tid + k * CT) * 4 + j];
            bpart[(size_t)blockIdx.x * 256 + 128 + tid * 4 + j] = s;
        }
    }
}

// ====== fp32 linear (layer-2, K=128 -> 64), LDS-staged A/h ======
__global__ __launch_bounds__(256) void linear2_k(
    const float* __restrict__ agg, const float* __restrict__ h,
    const float* __restrict__ coef, const float* __restrict__ wl,
    const float* __restrict__ bl, const float* __restrict__ wr,
    float* __restrict__ out, float* __restrict__ bpart, int n) {
    constexpr int DIN = 128, DOUT = 64, CT = 16, RB = 64, LDW = 132;
    __shared__ float Ash[RB * LDW];
    __shared__ float Hsh[RB * LDW];
    const int tid = threadIdx.x;
    const int base = blockIdx.x * RB;
    {
        const int sr = tid >> 2;
        const int sc = tid & 3;
        const int grow = min(base + sr, n - 1);
        const float* ar = agg + (size_t)grow * DIN;
        const float* hr = h + (size_t)grow * DIN;
#pragma unroll
        for (int c = 0; c < 8; c++) {
            const int col = (sc + c * 4) * 4;
            const float4 av = *(const float4*)(ar + col);
            float4 hv = *(const float4*)(hr + col);
            const float4 ca = *(const float4*)(coef + col);
            const float4 cb = *(const float4*)(coef + DIN + col);
            hv.x = trf(hv.x, ca.x, cb.x); hv.y = trf(hv.y, ca.y, cb.y);
            hv.z = trf(hv.z, ca.z, cb.z); hv.w = trf(hv.w, ca.w, cb.w);
            *(float4*)(Ash + sr * LDW + col) = av;
            *(float4*)(Hsh + sr * LDW + col) = hv;
        }
    }
    __syncthreads();
    const int ct = tid % CT;
    const int rt = tid / CT;
    const int col = ct * 4;
    const int row0 = base + rt * 4;
    float4 acc[4] = {};
#pragma unroll 2
    for (int k0 = 0; k0 < DIN; k0 += 4) {
        float4 wlv[4], wrv[4];
#pragma unroll
        for (int j = 0; j < 4; j++) {
            wlv[j] = *(const float4*)(wl + (size_t)(k0 + j) * DOUT + col);
            wrv[j] = *(const float4*)(wr + (size_t)(k0 + j) * DOUT + col);
        }
#pragma unroll
        for (int r = 0; r < 4; r++) {
            const float4 av = *(const float4*)(Ash + (rt * 4 + r) * LDW + k0);
            const float4 hv = *(const float4*)(Hsh + (rt * 4 + r) * LDW + k0);
#pragma unroll
            for (int j = 0; j < 4; j++) {
                const float aa = j == 0 ? av.x : j == 1 ? av.y : j == 2 ? av.z : av.w;
                const float bb = j == 0 ? hv.x : j == 1 ? hv.y : j == 2 ? hv.z : hv.w;
                acc[r].x += aa * wlv[j].x + bb * wrv[j].x;
                acc[r].y += aa * wlv[j].y + bb * wrv[j].y;
                acc[r].z += aa * wlv[j].z + bb * wrv[j].z;
                acc[r].w += aa * wlv[j].w + bb * wrv[j].w;
            }
        }
    }
    const float4 bv = *(const float4*)(bl + col);
    float cs[4] = {}, cq[4] = {};
#pragma unroll
    for (int r = 0; r < 4; r++) {
        if (row0 + r < n) {
            float4 o = acc[r];
            o.x += bv.x; o.y += bv.y; o.z += bv.z; o.w += bv.w;
            *(float4*)(out + (size_t)(row0 + r) * DOUT + col) = o;
            cs[0] += o.x; cq[0] += o.x * o.x;
            cs[1] += o.y; cq[1] += o.y * o.y;
            cs[2] += o.z; cq[2] += o.z * o.z;
            cs[3] += o.w; cq[3] += o.w * o.w;
        }
    }
    __syncthreads();
#pragma unroll
    for (int j = 0; j < 4; j++) Ash[tid * 4 + j] = cs[j];
    __syncthreads();
    if (tid < CT) {
#pragma unroll
        for (int j = 0; j < 4; j++) {
            float s = 0.f;
#pragma unroll
            for (int k = 0; k < 16; k++) s += Ash[(tid + k * CT) * 4 + j];
            bpart[(size_t)blockIdx.x * 128 + tid * 4 + j] = s;
        }
    }
    __syncthreads();
#pragma unroll
    for (int j = 0; j < 4; j++) Ash[tid * 4 + j] = cq[j];
    __syncthreads();
    if (tid < CT) {
#pragma unroll
        for (int j = 0; j < 4; j++) {
            float s = 0.f;
#pragma unroll
            for (int k = 0; k < 16; k++) s += Ash[(tid + k * CT) * 4 + j];
            bpart[(size_t)blockIdx.x * 128 + 64 + tid * 4 + j] = s;
        }
    }
}

// ====== sh1 linear: concat([x(32), rm(3)]) -> 128, LDS-staged, fused rm-gather ======
__global__ __launch_bounds__(256) void linear_shs_k(
    const float* __restrict__ aggx, const float* __restrict__ x,
    const float* __restrict__ rmb, const int* __restrict__ ptr,
    const int* __restrict__ csr,
    const float* __restrict__ wl, const float* __restrict__ bl,
    const float* __restrict__ wr, float* __restrict__ out,
    float* __restrict__ bpart, int n) {
    constexpr int DOUT = 128, CT = 32, RB = 32, LDW = 36;
    __shared__ float Ash[RB * LDW];
    __shared__ float Hsh[RB * LDW];
    __shared__ float Rsh[RB * 4], Msh[RB * 4];
    const int tid = threadIdx.x;
    const int base = blockIdx.x * RB;
    {
        const int sr = tid >> 3;
        const int col = (tid & 7) * 4;
        const int grow = min(base + sr, n - 1);
        *(float4*)(Ash + sr * LDW + col) = *(const float4*)(aggx + (size_t)grow * 32 + col);
        *(float4*)(Hsh + sr * LDW + col) = *(const float4*)(x + (size_t)grow * 32 + col);
        // fused gather of min over neighbors' rmb rows
        const int sub = tid & 7;
        const int e0 = ptr[grow];
        const int end2 = ptr[grow + 1];
        float q0 = FLTMAX, q1 = FLTMAX, q2 = FLTMAX;
        for (int e = e0 + sub; e < end2; e += 8) {
            const float* rr = rmb + (size_t)csr[e] * 3;
            q0 = fminf(q0, rr[0]);
            q1 = fminf(q1, rr[1]);
            q2 = fminf(q2, rr[2]);
        }
#pragma unroll
        for (int off = 1; off < 8; off <<= 1) {
            q0 = fminf(q0, __shfl_xor(q0, off));
            q1 = fminf(q1, __shfl_xor(q1, off));
            q2 = fminf(q2, __shfl_xor(q2, off));
        }
        if (sub == 0) {
            const bool em = (e0 == end2);
            Rsh[sr * 4 + 0] = em ? 0.f : q0;
            Rsh[sr * 4 + 1] = em ? 0.f : q1;
            Rsh[sr * 4 + 2] = em ? 0.f : q2;
            Msh[sr * 4 + 0] = rmb[(size_t)grow * 3 + 0];
            Msh[sr * 4 + 1] = rmb[(size_t)grow * 3 + 1];
            Msh[sr * 4 + 2] = rmb[(size_t)grow * 3 + 2];
        }
    }
    __syncthreads();
    const int ct = tid % CT;
    const int rt = tid / CT;
    const int col = ct * 4;
    const int row0 = base + rt * 4;
    float4 acc[4] = {};
#pragma unroll 2
    for (int k0 = 0; k0 < 32; k0 += 4) {
        float4 wlv[4], wrv[4];
#pragma unroll
        for (int j = 0; j < 4; j++) {
            wlv[j] = *(const float4*)(wl + (size_t)(k0 + j) * DOUT + col);
            wrv[j] = *(const float4*)(wr + (size_t)(k0 + j) * DOUT + col);
        }
#pragma unroll
        for (int r = 0; r < 4; r++) {
            const float4 av = *(const float4*)(Ash + (rt * 4 + r) * LDW + k0);
            const float4 hv = *(const float4*)(Hsh + (rt * 4 + r) * LDW + k0);
#pragma unroll
            for (int j = 0; j < 4; j++) {
                const float aa = j == 0 ? av.x : j == 1 ? av.y : j == 2 ? av.z : av.w;
                const float bb = j == 0 ? hv.x : j == 1 ? hv.y : j == 2 ? hv.z : hv.w;
                acc[r].x += aa * wlv[j].x + bb * wrv[j].x;
                acc[r].y += aa * wlv[j].y + bb * wrv[j].y;
                acc[r].z += aa * wlv[j].z + bb * wrv[j].z;
                acc[r].w += aa * wlv[j].w + bb * wrv[j].w;
            }
        }
    }
#pragma unroll
    for (int k = 0; k < 3; k++) {
        const float4 wlv = *(const float4*)(wl + (size_t)(32 + k) * DOUT + col);
        const float4 wrv = *(const float4*)(wr + (size_t)(32 + k) * DOUT + col);
#pragma unroll
        for (int r = 0; r < 4; r++) {
            const float a = Rsh[(rt * 4 + r) * 4 + k];
            const float b = Msh[(rt * 4 + r) * 4 + k];
            acc[r].x += a * wlv.x + b * wrv.x;
            acc[r].y += a * wlv.y + b * wrv.y;
            acc[r].z += a * wlv.z + b * wrv.z;
            acc[r].w += a * wlv.w + b * wrv.w;
        }
    }
    const float4 bv = *(const float4*)(bl + col);
    float cs[4] = {}, cq[4] = {};
#pragma unroll
    for (int r = 0; r < 4; r++) {
        if (row0 + r < n) {
            float4 o = acc[r];
            o.x += bv.x; o.y += bv.y; o.z += bv.z; o.w += bv.w;
            *(float4*)(out + (size_t)(row0 + r) * DOUT + col) = o;
            cs[0] += o.x; cq[0] += o.x * o.x;
            cs[1] += o.y; cq[1] += o.y * o.y;
            cs[2] += o.z; cq[2] += o.z * o.z;
            cs[3] += o.w; cq[3] += o.w * o.w;
        }
    }
    __syncthreads();
#pragma unroll
    for (int j = 0; j < 4; j++) Ash[tid * 4 + j] = cs[j];
    __syncthreads();
    if (tid < CT) {
#pragma unroll
        for (int j = 0; j < 4; j++) {
            float s = 0.f;
#pragma unroll
            for (int k = 0; k < 8; k++) s += Ash[(tid + k * CT) * 4 + j];
            bpart[(size_t)blockIdx.x * 256 + tid * 4 + j] = s;
        }
    }
    __syncthreads();
#pragma unroll
    for (int j = 0; j < 4; j++) Ash[tid * 4 + j] = cq[j];
    __syncthreads();
    if (tid < CT) {
#pragma unroll
        for (int j = 0; j < 4; j++) {
            float s = 0.f;
#pragma unroll
            for (int k = 0; k < 8; k++) s += Ash[(tid + k * CT) * 4 + j];
            bpart[(size_t)blockIdx.x * 256 + 128 + tid * 4 + j] = s;
        }
    }
}

// ---- reduce per-block partials into stats (s | s2), width = 2*D ----
__global__ __launch_bounds__(256) void reduce_part_k(
    const float* __restrict__ bpart, float* __restrict__ stats,
    int nb, int width) {
    const int c = threadIdx.x;
    if (c >= width) return;
    float s = 0.f;
    for (int k = blockIdx.x; k < nb; k += gridDim.x)
        s += bpart[(size_t)k * width + c];
    atomicAdd(&stats[c], s);
}

// ====== rm head fused: gather(h2,D=64) + 64->3 linear + log_softmax + labels ======
// gather uses sign-folded min; BN coef inlined from stats2.
__global__ __launch_bounds__(256) void rm_fused_k(
    const float* __restrict__ h2, const float* __restrict__ stats,
    const float* __restrict__ g, const float* __restrict__ be,
    const int* __restrict__ ptr, const int* __restrict__ csr,
    const float* __restrict__ wl, const float* __restrict__ bl,
    const float* __restrict__ wr, float* __restrict__ rmb,
    float* __restrict__ ls_out, float* __restrict__ lab, float invN, int n) {
    const int lane = threadIdx.x & 63;
    const int node = (blockIdx.x * 256 + threadIdx.x) >> 6;
    if (node >= n) return;
    float a, b;
    bncoef(stats[lane], stats[64 + lane], g[lane], be[lane], invN, a, b);
    const u32 sm = (a < 0.f) ? 0x80000000u : 0u;
    int e = ptr[node];
    const int end = ptr[node + 1];
    const bool empty = (e == end);
    float m = FLTMAX;
    for (; e + 15 < end; e += 16) {
        int s[16];
#pragma unroll
        for (int j = 0; j < 16; j++) s[j] = csr[e + j];
        float v[16];
#pragma unroll
        for (int j = 0; j < 16; j++) v[j] = h2[(size_t)s[j] * 64 + lane];
#pragma unroll
        for (int j = 0; j < 16; j++) m = sfmin(m, v[j], sm);
    }
    for (; e + 3 < end; e += 4) {
        int s[4];
#pragma unroll
        for (int j = 0; j < 4; j++) s[j] = csr[e + j];
        float v[4];
#pragma unroll
        for (int j = 0; j < 4; j++) v[j] = h2[(size_t)s[j] * 64 + lane];
#pragma unroll
        for (int j = 0; j < 4; j++) m = sfmin(m, v[j], sm);
    }
    for (; e < end; e++) m = sfmin(m, h2[(size_t)csr[e] * 64 + lane], sm);
    const float mv = empty ? 0.f : trf(sdec(m, sm), a, b);
    const float hv = trf(h2[(size_t)node * 64 + lane], a, b);
    float c0 = mv * wl[lane * 3 + 0] + hv * wr[lane * 3 + 0];
    float c1 = mv * wl[lane * 3 + 1] + hv * wr[lane * 3 + 1];
    float c2 = mv * wl[lane * 3 + 2] + hv * wr[lane * 3 + 2];
#pragma unroll
    for (int off = 1; off < 64; off <<= 1) {
        c0 += __shfl_xor(c0, off);
        c1 += __shfl_xor(c1, off);
        c2 += __shfl_xor(c2, off);
    }
    const float r0 = c0 + bl[0], r1 = c1 + bl[1], r2 = c2 + bl[2];
    if (lane < 3) {
        const float r = lane == 0 ? r0 : lane == 1 ? r1 : r2;
        rmb[(size_t)node * 3 + lane] = r;
        const float mx = fmaxf(r0, fmaxf(r1, r2));
        const float lse = mx + logf(expf(r0 - mx) + expf(r1 - mx) + expf(r2 - mx));
        ls_out[(size_t)node * 3 + lane] = r - lse;
        if (lane == 0) lab[node] = (r2 > r0 && r2 > r1) ? 1.f : 0.f;
    }
}

// ====== final heads: wave-per-node, coalesced + shuffle reduce; coef inlined ======
__global__ __launch_bounds__(256) void final_k(
    const float* __restrict__ rtmd, const float* __restrict__ stats,
    const float* __restrict__ gR, const float* __restrict__ bR,
    const float* __restrict__ gM, const float* __restrict__ bM,
    const float* __restrict__ rtw, const float* __restrict__ rtb,
    const float* __restrict__ mdw, const float* __restrict__ mdb,
    const float* __restrict__ lab, float* __restrict__ out_rt,
    float* __restrict__ out_md, float invN, int n) {
    const int lane = threadIdx.x & 63;
    const int node = (blockIdx.x * 256 + threadIdx.x) >> 6;
    if (node >= n) return;
    float aR, bRc, aM, bMc;
    bncoef(stats[lane], stats[128 + lane], gR[lane], bR[lane], invN, aR, bRc);
    bncoef(stats[64 + lane], stats[192 + lane], gM[lane], bM[lane], invN, aM, bMc);
    const float* rr = rtmd + (size_t)node * 128;
    float a = trf(rr[lane], aR, bRc) * rtw[lane];
    float b = trf(rr[64 + lane], aM, bMc) * mdw[lane];
#pragma unroll
    for (int off = 1; off < 64; off <<= 1) {
        a += __shfl_xor(a, off);
        b += __shfl_xor(b, off);
    }
    if (lane == 0) {
        const float l = lab[node];
        out_rt[node] = (a + rtb[0]) * l;
        out_md[node] = (b + mdb[0]) * l;
    }
}

extern "C" void kernel_launch(void* const* d_in, const int* in_sizes, int n_in,
                              void* d_out, int out_size, void* d_ws, size_t ws_size,
                              hipStream_t stream) {
    const float* x = (const float*)d_in[0];
    const int* ei = (const int*)d_in[1];
    const int E = in_sizes[1] / 2;
    const int n = in_sizes[0] / 32;
    const int* src = ei;
    const int* dst = ei + E;

    const float* rm1_wl = (const float*)d_in[2];
    const float* rm1_bl = (const float*)d_in[3];
    const float* rm1_wr = (const float*)d_in[4];
    const float* rmn1_g = (const float*)d_in[5];
    const float* rmn1_b = (const float*)d_in[6];
    const float* rm2_wl = (const float*)d_in[7];
    const float* rm2_bl = (const float*)d_in[8];
    const float* rm2_wr = (const float*)d_in[9];
    const float* rmn2_g = (const float*)d_in[10];
    const float* rmn2_b = (const float*)d_in[11];
    const float* rm4_wl = (const float*)d_in[12];
    const float* rm4_bl = (const float*)d_in[13];
    const float* rm4_wr = (const float*)d_in[14];
    const float* sh1_wl = (const float*)d_in[15];
    const float* sh1_bl = (const float*)d_in[16];
    const float* sh1_wr = (const float*)d_in[17];
    const float* shn1_g = (const float*)d_in[18];
    const float* shn1_b = (const float*)d_in[19];
    const float* rt1_wl = (const float*)d_in[20];
    const float* rt1_bl = (const float*)d_in[21];
    const float* rt1_wr = (const float*)d_in[22];
    const float* rtn1_g = (const float*)d_in[23];
    const float* rtn1_b = (const float*)d_in[24];
    const float* rt3_w = (const float*)d_in[25];
    const float* rt3_b = (const float*)d_in[26];
    const float* md1_wl = (const float*)d_in[27];
    const float* md1_bl = (const float*)d_in[28];
    const float* md1_wr = (const float*)d_in[29];
    const float* mdn1_g = (const float*)d_in[30];
    const float* mdn1_b = (const float*)d_in[31];
    const float* md3_w = (const float*)d_in[32];
    const float* md3_b = (const float*)d_in[33];

    // workspace layout; shbuf serves as fp32 aggB (layer 2), then bf16 Acat (dual)
    char* w = (char*)d_ws;
    float* aggX  = (float*)w; w += (size_t)n * 32 * 4;
    float* h1    = (float*)w; w += (size_t)n * 128 * 4;   // h1 raw, later h3 raw
    char*  shbuf = w;         w += (size_t)n * 512;       // aggB fp32 [n][128] | Acat bf16 [n][256]
    float* h2rt  = (float*)w; w += (size_t)n * 128 * 4;   // h2 [n][64], later rtmd [n][128]
    float* rmb   = (float*)w; w += (size_t)n * 3 * 4;
    float* aggR  = (float*)w; w += (size_t)n * 3 * 4;     // (unused, kept for layout)
    float* lab   = (float*)w; w += (size_t)n * 4;
    float* stats = (float*)w; w += 1024 * 4;
    float* coef  = (float*)w; w += 1024 * 4;
    u16*   WTD   = (u16*)w;   w += (size_t)128 * 256 * 2;
    int* ptr  = (int*)w; w += (size_t)(n + 1) * 4;
    int* pos  = (int*)w; w += (size_t)n * 4;
    int* bsum = (int*)w; w += 1024 * 4;
    int* csr  = (int*)w; w += (size_t)E * 4;

    float* aggB = (float*)shbuf;
    u16*   Acat = (u16*)shbuf;
    float* h2 = h2rt;
    float* rtmd = h2rt;
    float* stats1 = stats, *stats2 = stats + 256, *statsSh = stats + 512, *statsD = stats + 768;
    float* coef1 = coef;   // exported by gather_min128 block 0, read by linear2

    // stats-partial buffers reuse dead regions (stream-ordered, no ws growth)
    float* bp1  = (float*)shbuf;
    float* bp2  = rmb;
    float* bpSh = (float*)shbuf;
    float* bpD  = rmb;

    float* out = (float*)d_out;
    float* out_ls = out;
    float* out_rt = out + (size_t)3 * n;
    float* out_md = out + (size_t)4 * n;

    const float invN = 1.f / (float)n;
    auto cdiv = [](int a, int b) { return (a + b - 1) / b; };
    const int nb = cdiv(n, 256);
    const int nb32 = cdiv(n, 32);
    const int nb64 = cdiv(n, 64);
    const int lo_step = cdiv(n, 8);

    hipMemsetAsync(stats, 0, 1024 * 4, stream);
    hipMemsetAsync(pos, 0, (size_t)n * 4, stream);

    // ---- CSR build (XCD-partitioned hist + fill) + dual-weight prep
    hist_part_k<<<cdiv(E, 256) * 8, 256, 0, stream>>>(dst, pos, E, lo_step);
    wprep_dual_k<<<128, 256, 0, stream>>>(rt1_wl, rt1_wr, md1_wl, md1_wr, WTD);
    scan_block_k<<<nb, 256, 0, stream>>>(pos, ptr, bsum, n);
    scan_add_k<<<nb, 256, 0, stream>>>(ptr, pos, bsum, n, E);
    csr_fill_part_k<<<cdiv(E, 256) * 8, 256, 0, stream>>>(src, dst, pos, csr, E, lo_step);

    // ---- layer 1 (fp32): agg(x) -> linear (fused stats -> bpart) -> h1
    gather_min32_k<<<cdiv(n, 8), 256, 0, stream>>>(x, ptr, csr, aggX, n);
    linear1s_k<<<nb32, 256, 0, stream>>>(aggX, x, rm1_wl, rm1_bl, rm1_wr, h1, bp1, n);
    reduce_part_k<<<64, 256, 0, stream>>>(bp1, stats1, nb32, 256);

    // ---- layer 2 (fp32, label-critical): gather(bnrelu(h1)) [coef1 inline+export]
    gather_min128_k<<<cdiv(n, 4), 256, 0, stream>>>(h1, ptr, csr, stats1, rmn1_g, rmn1_b,
                                                    coef1, aggB, invN, n);
    linear2_k<<<nb64, 256, 0, stream>>>(aggB, h1, coef1, rm2_wl, rm2_bl, rm2_wr, h2, bp2, n);
    reduce_part_k<<<64, 256, 0, stream>>>(bp2, stats2, nb64, 128);

    // ---- rm head (fp32): fused gather + linear + log_softmax + labels [coef2 inline]
    rm_fused_k<<<cdiv(n, 4), 256, 0, stream>>>(h2, stats2, rmn2_g, rmn2_b, ptr, csr,
                                               rm4_wl, rm4_bl, rm4_wr, rmb, out_ls, lab, invN, n);

    // ---- sh1 (fp32): linear concat([x,rm]) with fused rm-gather -> h3 (h1 buf)
    linear_shs_k<<<nb32, 256, 0, stream>>>(aggX, x, rmb, ptr, csr,
                                           sh1_wl, sh1_bl, sh1_wr, h1, bpSh, n);
    reduce_part_k<<<64, 256, 0, stream>>>(bpSh, statsSh, nb32, 256);

    // ---- dual rt/md (bf16 MFMA): convert [coefSh inline] -> gather -> GEMM
    convert_k<<<cdiv(n * 32, 256), 256, 0, stream>>>(h1, statsSh, shn1_g, shn1_b, Acat, invN, n);
    gather_bf_k<<<cdiv(n, 8), 256, 0, stream>>>(Acat, ptr, csr, n);
    gemm_bf_k<<<nb64, 256, 0, stream>>>(Acat, WTD, rt1_bl, md1_bl, rtmd, bpD, n);
    reduce_part_k<<<64, 256, 0, stream>>>(bpD, statsD, nb64, 256);

    // ---- final heads [coefRt/Md inline]
    final_k<<<cdiv(n, 4), 256, 0, stream>>>(rtmd, statsD, rtn1_g, rtn1_b, mdn1_g, mdn1_b,
                                            rt3_w, rt3_b, md3_w, md3_b, lab,
                                            out_rt, out_md, invN, n);
}

// Round 8
// 850.566 us; speedup vs baseline: 1.7553x; 1.0103x over previous
//
#include <hip/hip_runtime.h>

#define FLTMAX 3.402823466e+38f
#define DEV __device__ __forceinline__

typedef unsigned short u16;
typedef unsigned int u32;
typedef __bf16 bf16_t;
typedef bf16_t bf16x8 __attribute__((ext_vector_type(8)));
typedef float f32x4 __attribute__((ext_vector_type(4)));

union U16x8 { uint4 u; bf16x8 b; };

DEV float trf(float v, float a, float b) { return fmaxf(fmaf(v, a, b), 0.f); }

// sign-folded min helpers: track min of (v ^ sm); sm=0x80000000 turns it into max-tracking
DEV float sfmin(float m, float v, u32 sm) {
    return fminf(m, __uint_as_float(__float_as_uint(v) ^ sm));
}
DEV float sdec(float m, u32 sm) { return __uint_as_float(__float_as_uint(m) ^ sm); }

// round-to-nearest-even fp32 -> bf16 bits (finite inputs)
DEV u16 f2bf(float f) {
    u32 u = __float_as_uint(f);
    return (u16)((u + 0x7FFFu + ((u >> 16) & 1u)) >> 16);
}

// BN coef from stats: a = rsqrt(var+eps)*g, b = beta - mu*a
DEV void bncoef(float s, float s2, float g, float be, float invN, float& a, float& b) {
    const float mu = s * invN;
    const float var = s2 * invN - mu * mu;
    a = rsqrtf(var + 1e-5f) * g;
    b = be - mu * a;
}

// ================= CSR build =================
// simple histogram: deg[] atomics are cold/spread (400KB) — XCD partition not worth 8x dst re-read (R7)
__global__ __launch_bounds__(256) void hist_k(const int* __restrict__ dst,
                                              int* __restrict__ deg, int E) {
    int e = blockIdx.x * 256 + threadIdx.x;
    if (e >= E) return;
    atomicAdd(&deg[dst[e]], 1);
}

__global__ __launch_bounds__(256) void scan_block_k(const int* __restrict__ deg,
                                                    int* __restrict__ ptr,
                                                    int* __restrict__ bsum, int n) {
    __shared__ int ls[256];
    int i = blockIdx.x * 256 + threadIdx.x;
    int v = (i < n) ? deg[i] : 0;
    ls[threadIdx.x] = v;
    __syncthreads();
#pragma unroll
    for (int off = 1; off < 256; off <<= 1) {
        int a = (threadIdx.x >= off) ? ls[threadIdx.x - off] : 0;
        __syncthreads();
        ls[threadIdx.x] += a;
        __syncthreads();
    }
    if (i < n) ptr[i] = ls[threadIdx.x] - v;
    if (threadIdx.x == 255) bsum[blockIdx.x] = ls[255];
}

// scan_add with inline prefix over raw bsum
__global__ __launch_bounds__(256) void scan_add_k(int* __restrict__ ptr,
                                                  int* __restrict__ pos,
                                                  const int* __restrict__ bsum,
                                                  int n, int E) {
    __shared__ int shw[4];
    const int tid = threadIdx.x;
    int part = 0;
    for (int k = tid; k < blockIdx.x; k += 256) part += bsum[k];
#pragma unroll
    for (int off = 1; off < 64; off <<= 1) part += __shfl_xor(part, off);
    if ((tid & 63) == 0) shw[tid >> 6] = part;
    __syncthreads();
    const int boff = shw[0] + shw[1] + shw[2] + shw[3];
    const int i = blockIdx.x * 256 + tid;
    if (i == 0) ptr[n] = E;
    if (i < n) {
        int p = ptr[i] + boff;
        ptr[i] = p;
        pos[i] = p;
    }
}

// XCD-partitioned fill: partition = blockIdx & 7
__global__ __launch_bounds__(256) void csr_fill_part_k(
    const int* __restrict__ src, const int* __restrict__ dst,
    int* __restrict__ pos, int* __restrict__ csr, int E, int lo_step) {
    const int part = blockIdx.x & 7;
    const int e = (blockIdx.x >> 3) * 256 + threadIdx.x;
    if (e >= E) return;
    const int d = dst[e];
    const int lo = part * lo_step;
    const int hi = lo + lo_step;
    if (d < lo || d >= hi) return;
    const int p = atomicAdd(&pos[d], 1);
    csr[p] = src[e];
}

// ====== fp32 gather min (layer-1 x, D=32) ======
__global__ __launch_bounds__(256) void gather_min32_k(
    const float* __restrict__ feat, const int* __restrict__ ptr,
    const int* __restrict__ csr, float* __restrict__ agg, int n) {
    const int lane = threadIdx.x & 63;
    const int wave = (blockIdx.x * 256 + threadIdx.x) >> 6;
    const int node = wave * 2 + (lane >> 5);
    if (node >= n) return;
    const int fl = lane & 31;
    int e = ptr[node];
    const int end = ptr[node + 1];
    const bool empty = (e == end);
    float m = FLTMAX;
    for (; e + 7 < end; e += 8) {
        int s[8];
#pragma unroll
        for (int j = 0; j < 8; j++) s[j] = csr[e + j];
        float v[8];
#pragma unroll
        for (int j = 0; j < 8; j++) v[j] = feat[(size_t)s[j] * 32 + fl];
#pragma unroll
        for (int j = 0; j < 8; j++) m = fminf(m, v[j]);
    }
    for (; e < end; e++) m = fminf(m, feat[(size_t)csr[e] * 32 + fl]);
    agg[(size_t)node * 32 + fl] = empty ? 0.f : m;
}

// ====== fp32 gather min D=128, fused BN+ReLU (sign-folded) ======
// 1 node per 64-lane wave, float2/lane. Inline coef from stats; block0 exports coef1.
__global__ __launch_bounds__(256) void gather_min128_k(
    const float* __restrict__ feat, const int* __restrict__ ptr,
    const int* __restrict__ csr, const float* __restrict__ stats,
    const float* __restrict__ g, const float* __restrict__ be,
    float* __restrict__ coef_out, float* __restrict__ agg, float invN, int n) {
    const int lane = threadIdx.x & 63;
    const int node = (blockIdx.x * 256 + threadIdx.x) >> 6;
    if (node >= n) return;
    const int fl = lane * 2;
    float ca0, cb0, ca1, cb1;
    bncoef(stats[fl], stats[128 + fl], g[fl], be[fl], invN, ca0, cb0);
    bncoef(stats[fl + 1], stats[129 + fl], g[fl + 1], be[fl + 1], invN, ca1, cb1);
    if (blockIdx.x == 0 && threadIdx.x < 64) {   // export for linear2
        coef_out[fl] = ca0; coef_out[fl + 1] = ca1;
        coef_out[128 + fl] = cb0; coef_out[129 + fl] = cb1;
    }
    const u32 sm0 = (ca0 < 0.f) ? 0x80000000u : 0u;
    const u32 sm1 = (ca1 < 0.f) ? 0x80000000u : 0u;
    int e = ptr[node];
    const int end = ptr[node + 1];
    const bool empty = (e == end);
    float m0 = FLTMAX, m1 = FLTMAX;
    for (; e + 7 < end; e += 8) {
        int s[8];
#pragma unroll
        for (int j = 0; j < 8; j++) s[j] = csr[e + j];
        float2 v[8];
#pragma unroll
        for (int j = 0; j < 8; j++) v[j] = *(const float2*)(feat + (size_t)s[j] * 128 + fl);
#pragma unroll
        for (int j = 0; j < 8; j++) {
            m0 = sfmin(m0, v[j].x, sm0);
            m1 = sfmin(m1, v[j].y, sm1);
        }
    }
    for (; e + 3 < end; e += 4) {
        int s[4];
#pragma unroll
        for (int j = 0; j < 4; j++) s[j] = csr[e + j];
        float2 v[4];
#pragma unroll
        for (int j = 0; j < 4; j++) v[j] = *(const float2*)(feat + (size_t)s[j] * 128 + fl);
#pragma unroll
        for (int j = 0; j < 4; j++) {
            m0 = sfmin(m0, v[j].x, sm0);
            m1 = sfmin(m1, v[j].y, sm1);
        }
    }
    for (; e < end; e++) {
        const float2 v = *(const float2*)(feat + (size_t)csr[e] * 128 + fl);
        m0 = sfmin(m0, v.x, sm0);
        m1 = sfmin(m1, v.y, sm1);
    }
    float2 o;
    o.x = empty ? 0.f : trf(sdec(m0, sm0), ca0, cb0);
    o.y = empty ? 0.f : trf(sdec(m1, sm1), ca1, cb1);
    *(float2*)(agg + (size_t)node * 128 + fl) = o;
}

// ====== bf16 gather min over A_cat right half -> left half ======
// 2 nodes/wave: 32 lanes x uint2 (4 bf16) per neighbor row.
__global__ __launch_bounds__(256) void gather_bf_k(
    u16* __restrict__ Acat, const int* __restrict__ ptr,
    const int* __restrict__ csr, int n) {
    const int lane = threadIdx.x & 63;
    const int wave = (blockIdx.x * 256 + threadIdx.x) >> 6;
    const int node = wave * 2 + (lane >> 5);
    if (node >= n) return;
    const int fl = (lane & 31) * 4;   // u16 index; 32 lanes x 4 = 128 cols
    int e = ptr[node];
    const int end = ptr[node + 1];
    uint2 outv = {0u, 0u};
    if (e != end) {
        float m0 = FLTMAX, m1 = FLTMAX, m2 = FLTMAX, m3 = FLTMAX;
        for (; e + 7 < end; e += 8) {
            int s[8];
#pragma unroll
            for (int j = 0; j < 8; j++) s[j] = csr[e + j];
            uint2 v[8];
#pragma unroll
            for (int j = 0; j < 8; j++) v[j] = *(const uint2*)(Acat + (size_t)s[j] * 256 + 128 + fl);
#pragma unroll
            for (int j = 0; j < 8; j++) {
                m0 = fminf(m0, __uint_as_float(v[j].x << 16));
                m1 = fminf(m1, __uint_as_float(v[j].x & 0xffff0000u));
                m2 = fminf(m2, __uint_as_float(v[j].y << 16));
                m3 = fminf(m3, __uint_as_float(v[j].y & 0xffff0000u));
            }
        }
        for (; e < end; e++) {
            const uint2 v = *(const uint2*)(Acat + (size_t)csr[e] * 256 + 128 + fl);
            m0 = fminf(m0, __uint_as_float(v.x << 16));
            m1 = fminf(m1, __uint_as_float(v.x & 0xffff0000u));
            m2 = fminf(m2, __uint_as_float(v.y << 16));
            m3 = fminf(m3, __uint_as_float(v.y & 0xffff0000u));
        }
        outv.x = (__float_as_uint(m0) >> 16) | (__float_as_uint(m1) & 0xffff0000u);
        outv.y = (__float_as_uint(m2) >> 16) | (__float_as_uint(m3) & 0xffff0000u);
    }
    *(uint2*)(Acat + (size_t)node * 256 + fl) = outv;
}

// ====== convert bn_relu(h) (D=128) -> bf16 into A_cat right half (coef inlined) ======
__global__ __launch_bounds__(256) void convert_k(
    const float* __restrict__ h, const float* __restrict__ stats,
    const float* __restrict__ g, const float* __restrict__ be,
    u16* __restrict__ Acat, float invN, int n) {
    int t = blockIdx.x * 256 + threadIdx.x;
    int total = n * 32;
    if (t >= total) return;
    int i = t >> 5;
    int dq = (t & 31) * 4;
    const float4 s1 = *(const float4*)(stats + dq);
    const float4 s2 = *(const float4*)(stats + 128 + dq);
    const float4 gv = *(const float4*)(g + dq);
    const float4 ev = *(const float4*)(be + dq);
    float4 ca, cb;
    bncoef(s1.x, s2.x, gv.x, ev.x, invN, ca.x, cb.x);
    bncoef(s1.y, s2.y, gv.y, ev.y, invN, ca.y, cb.y);
    bncoef(s1.z, s2.z, gv.z, ev.z, invN, ca.z, cb.z);
    bncoef(s1.w, s2.w, gv.w, ev.w, invN, ca.w, cb.w);
    const float4 hv = *(const float4*)(h + (size_t)i * 128 + dq);
    ushort4 o;
    o.x = f2bf(trf(hv.x, ca.x, cb.x));
    o.y = f2bf(trf(hv.y, ca.y, cb.y));
    o.z = f2bf(trf(hv.z, ca.z, cb.z));
    o.w = f2bf(trf(hv.w, ca.w, cb.w));
    *(ushort4*)(Acat + (size_t)i * 256 + 128 + dq) = o;
}

// ====== weight prep (dual, one launch): WT row c: c<64 -> rt pair, else md pair ======
__global__ __launch_bounds__(256) void wprep_dual_k(
    const float* __restrict__ rwl, const float* __restrict__ rwr,
    const float* __restrict__ mwl, const float* __restrict__ mwr,
    u16* __restrict__ WT) {
    int t = blockIdx.x * 256 + threadIdx.x;   // 128*256 total
    int c = t >> 8;
    int k = t & 255;
    const float* wlp = (c < 64) ? rwl : mwl;
    const float* wrp = (c < 64) ? rwr : mwr;
    const int cc = c & 63;
    float v = (k < 128) ? wlp[k * 64 + cc] : wrp[(k - 128) * 64 + cc];
    WT[(size_t)c * 256 + k] = f2bf(v);
}

// ====== bf16 MFMA GEMM: out[n][128] = A_cat[n][256] @ W_cat[256][128] + bias ======
// fused per-block column stats -> bpart[blk][256] (s | s2)
__global__ __launch_bounds__(256) void gemm_bf_k(
    const u16* __restrict__ A, const u16* __restrict__ WT,
    const float* __restrict__ bl1, const float* __restrict__ bl2,
    float* __restrict__ out, float* __restrict__ bpart, int n) {
    constexpr int NT = 8;
    __shared__ float bs[256];
    const int tid = threadIdx.x;
    bs[tid] = 0.f;
    const int wave = tid >> 6, lane = tid & 63;
    const int quad = lane >> 4, l16 = lane & 15;
    const int row0 = blockIdx.x * 64 + wave * 16;
    const int rowA = min(row0 + l16, n - 1);
    const uint4* Arow = (const uint4*)(A + (size_t)rowA * 256) + quad;

    bf16x8 a[8];
#pragma unroll
    for (int kc = 0; kc < 8; kc++) {
        U16x8 u; u.u = Arow[kc * 4];
        a[kc] = u.b;
    }
    f32x4 acc[NT];
#pragma unroll
    for (int i = 0; i < NT; i++) acc[i] = (f32x4){0.f, 0.f, 0.f, 0.f};
#pragma unroll
    for (int nt = 0; nt < NT; nt++) {
        const uint4* Brow = (const uint4*)(WT + (size_t)(nt * 16 + l16) * 256) + quad;
#pragma unroll
        for (int kc = 0; kc < 8; kc++) {
            U16x8 u; u.u = Brow[kc * 4];
            acc[nt] = __builtin_amdgcn_mfma_f32_16x16x32_bf16(a[kc], u.b, acc[nt], 0, 0, 0);
        }
    }
    __syncthreads();   // bs[] zeroed by all waves before atomics below
#pragma unroll
    for (int nt = 0; nt < NT; nt++) {
        const int col = nt * 16 + l16;
        const float bias = (col < 64) ? bl1[col] : bl2[col - 64];
        float s = 0.f, q = 0.f;
#pragma unroll
        for (int r = 0; r < 4; r++) {
            const int row = row0 + quad * 4 + r;
            if (row < n) {
                const float o = acc[nt][r] + bias;
                out[(size_t)row * 128 + col] = o;
                s += o;
                q += o * o;
            }
        }
        atomicAdd(&bs[col], s);
        atomicAdd(&bs[128 + col], q);
    }
    __syncthreads();
    bpart[(size_t)blockIdx.x * 256 + tid] = bs[tid];
}

// ====== fp32 linear layer-1 (K=32 -> 128), LDS-staged A/h, fused col-stats ======
__global__ __launch_bounds__(256) void linear1s_k(
    const float* __restrict__ agg, const float* __restrict__ h,
    const float* __restrict__ wl, const float* __restrict__ bl,
    const float* __restrict__ wr, float* __restrict__ out,
    float* __restrict__ bpart, int n) {
    constexpr int DOUT = 128, CT = 32, RB = 32, LDW = 36;
    __shared__ float Ash[RB * LDW];   // 4.6 KB (reused as stats scratch)
    __shared__ float Hsh[RB * LDW];   // 4.6 KB
    const int tid = threadIdx.x;
    const int base = blockIdx.x * RB;
    {   // stage: thread = (row = tid>>3, chunk = tid&7); col = chunk*4
        const int sr = tid >> 3;
        const int col = (tid & 7) * 4;
        const int grow = min(base + sr, n - 1);
        *(float4*)(Ash + sr * LDW + col) = *(const float4*)(agg + (size_t)grow * 32 + col);
        *(float4*)(Hsh + sr * LDW + col) = *(const float4*)(h + (size_t)grow * 32 + col);
    }
    __syncthreads();
    const int ct = tid % CT;
    const int rt = tid / CT;
    const int col = ct * 4;
    const int row0 = base + rt * 4;
    float4 acc[4] = {};
#pragma unroll 2
    for (int k0 = 0; k0 < 32; k0 += 4) {
        float4 wlv[4], wrv[4];
#pragma unroll
        for (int j = 0; j < 4; j++) {
            wlv[j] = *(const float4*)(wl + (size_t)(k0 + j) * DOUT + col);
            wrv[j] = *(const float4*)(wr + (size_t)(k0 + j) * DOUT + col);
        }
#pragma unroll
        for (int r = 0; r < 4; r++) {
            const float4 av = *(const float4*)(Ash + (rt * 4 + r) * LDW + k0);
            const float4 hv = *(const float4*)(Hsh + (rt * 4 + r) * LDW + k0);
#pragma unroll
            for (int j = 0; j < 4; j++) {
                const float aa = j == 0 ? av.x : j == 1 ? av.y : j == 2 ? av.z : av.w;
                const float bb = j == 0 ? hv.x : j == 1 ? hv.y : j == 2 ? hv.z : hv.w;
                acc[r].x += aa * wlv[j].x + bb * wrv[j].x;
                acc[r].y += aa * wlv[j].y + bb * wrv[j].y;
                acc[r].z += aa * wlv[j].z + bb * wrv[j].z;
                acc[r].w += aa * wlv[j].w + bb * wrv[j].w;
            }
        }
    }
    const float4 bv = *(const float4*)(bl + col);
    float cs[4] = {}, cq[4] = {};
#pragma unroll
    for (int r = 0; r < 4; r++) {
        if (row0 + r < n) {
            float4 o = acc[r];
            o.x += bv.x; o.y += bv.y; o.z += bv.z; o.w += bv.w;
            *(float4*)(out + (size_t)(row0 + r) * DOUT + col) = o;
            cs[0] += o.x; cq[0] += o.x * o.x;
            cs[1] += o.y; cq[1] += o.y * o.y;
            cs[2] += o.z; cq[2] += o.z * o.z;
            cs[3] += o.w; cq[3] += o.w * o.w;
        }
    }
    // block-level column reduce (8 row-threads per column group) -> bpart
    __syncthreads();
#pragma unroll
    for (int j = 0; j < 4; j++) Ash[tid * 4 + j] = cs[j];
    __syncthreads();
    if (tid < CT) {
#pragma unroll
        for (int j = 0; j < 4; j++) {
            float s = 0.f;
#pragma unroll
            for (int k = 0; k < 8; k++) s += Ash[(tid + k * CT) * 4 + j];
            bpart[(size_t)blockIdx.x * 256 + tid * 4 + j] = s;
        }
    }
    __syncthreads();
#pragma unroll
    for (int j = 0; j < 4; j++) Ash[tid * 4 + j] = cq[j];
    __syncthreads();
    if (tid < CT) {
#pragma unroll
        for (int j = 0; j < 4; j++) {
            float s = 0.f;
#pragma unroll
            for (int k = 0; k < 8; k++) s += Ash[(tid + k * CT) * 4 + j];
            bpart[(size_t)blockIdx.x * 256 + 128 + tid * 4 + j] = s;
        }
    }
}

// ====== fp32 linear (layer-2, K=128 -> 64), LDS-staged A/h ======
__global__ __launch_bounds__(256) void linear2_k(
    const float* __restrict__ agg, const float* __restrict__ h,
    const float* __restrict__ coef, const float* __restrict__ wl,
    const float* __restrict__ bl, const float* __restrict__ wr,
    float* __restrict__ out, float* __restrict__ bpart, int n) {
    constexpr int DIN = 128, DOUT = 64, CT = 16, RB = 64, LDW = 132;
    __shared__ float Ash[RB * LDW];
    __shared__ float Hsh[RB * LDW];
    const int tid = threadIdx.x;
    const int base = blockIdx.x * RB;
    {
        const int sr = tid >> 2;
        const int sc = tid & 3;
        const int grow = min(base + sr, n - 1);
        const float* ar = agg + (size_t)grow * DIN;
        const float* hr = h + (size_t)grow * DIN;
#pragma unroll
        for (int c = 0; c < 8; c++) {
            const int col = (sc + c * 4) * 4;
            const float4 av = *(const float4*)(ar + col);
            float4 hv = *(const float4*)(hr + col);
            const float4 ca = *(const float4*)(coef + col);
            const float4 cb = *(const float4*)(coef + DIN + col);
            hv.x = trf(hv.x, ca.x, cb.x); hv.y = trf(hv.y, ca.y, cb.y);
            hv.z = trf(hv.z, ca.z, cb.z); hv.w = trf(hv.w, ca.w, cb.w);
            *(float4*)(Ash + sr * LDW + col) = av;
            *(float4*)(Hsh + sr * LDW + col) = hv;
        }
    }
    __syncthreads();
    const int ct = tid % CT;
    const int rt = tid / CT;
    const int col = ct * 4;
    const int row0 = base + rt * 4;
    float4 acc[4] = {};
#pragma unroll 2
    for (int k0 = 0; k0 < DIN; k0 += 4) {
        float4 wlv[4], wrv[4];
#pragma unroll
        for (int j = 0; j < 4; j++) {
            wlv[j] = *(const float4*)(wl + (size_t)(k0 + j) * DOUT + col);
            wrv[j] = *(const float4*)(wr + (size_t)(k0 + j) * DOUT + col);
        }
#pragma unroll
        for (int r = 0; r < 4; r++) {
            const float4 av = *(const float4*)(Ash + (rt * 4 + r) * LDW + k0);
            const float4 hv = *(const float4*)(Hsh + (rt * 4 + r) * LDW + k0);
#pragma unroll
            for (int j = 0; j < 4; j++) {
                const float aa = j == 0 ? av.x : j == 1 ? av.y : j == 2 ? av.z : av.w;
                const float bb = j == 0 ? hv.x : j == 1 ? hv.y : j == 2 ? hv.z : hv.w;
                acc[r].x += aa * wlv[j].x + bb * wrv[j].x;
                acc[r].y += aa * wlv[j].y + bb * wrv[j].y;
                acc[r].z += aa * wlv[j].z + bb * wrv[j].z;
                acc[r].w += aa * wlv[j].w + bb * wrv[j].w;
            }
        }
    }
    const float4 bv = *(const float4*)(bl + col);
    float cs[4] = {}, cq[4] = {};
#pragma unroll
    for (int r = 0; r < 4; r++) {
        if (row0 + r < n) {
            float4 o = acc[r];
            o.x += bv.x; o.y += bv.y; o.z += bv.z; o.w += bv.w;
            *(float4*)(out + (size_t)(row0 + r) * DOUT + col) = o;
            cs[0] += o.x; cq[0] += o.x * o.x;
            cs[1] += o.y; cq[1] += o.y * o.y;
            cs[2] += o.z; cq[2] += o.z * o.z;
            cs[3] += o.w; cq[3] += o.w * o.w;
        }
    }
    __syncthreads();
#pragma unroll
    for (int j = 0; j < 4; j++) Ash[tid * 4 + j] = cs[j];
    __syncthreads();
    if (tid < CT) {
#pragma unroll
        for (int j = 0; j < 4; j++) {
            float s = 0.f;
#pragma unroll
            for (int k = 0; k < 16; k++) s += Ash[(tid + k * CT) * 4 + j];
            bpart[(size_t)blockIdx.x * 128 + tid * 4 + j] = s;
        }
    }
    __syncthreads();
#pragma unroll
    for (int j = 0; j < 4; j++) Ash[tid * 4 + j] = cq[j];
    __syncthreads();
    if (tid < CT) {
#pragma unroll
        for (int j = 0; j < 4; j++) {
            float s = 0.f;
#pragma unroll
            for (int k = 0; k < 16; k++) s += Ash[(tid + k * CT) * 4 + j];
            bpart[(size_t)blockIdx.x * 128 + 64 + tid * 4 + j] = s;
        }
    }
}

// ====== sh1 linear: concat([x(32), rm(3)]) -> 128, LDS-staged, fused rm-gather ======
__global__ __launch_bounds__(256) void linear_shs_k(
    const float* __restrict__ aggx, const float* __restrict__ x,
    const float* __restrict__ rmb, const int* __restrict__ ptr,
    const int* __restrict__ csr,
    const float* __restrict__ wl, const float* __restrict__ bl,
    const float* __restrict__ wr, float* __restrict__ out,
    float* __restrict__ bpart, int n) {
    constexpr int DOUT = 128, CT = 32, RB = 32, LDW = 36;
    __shared__ float Ash[RB * LDW];
    __shared__ float Hsh[RB * LDW];
    __shared__ float Rsh[RB * 4], Msh[RB * 4];
    const int tid = threadIdx.x;
    const int base = blockIdx.x * RB;
    {
        const int sr = tid >> 3;
        const int col = (tid & 7) * 4;
        const int grow = min(base + sr, n - 1);
        *(float4*)(Ash + sr * LDW + col) = *(const float4*)(aggx + (size_t)grow * 32 + col);
        *(float4*)(Hsh + sr * LDW + col) = *(const float4*)(x + (size_t)grow * 32 + col);
        // fused gather of min over neighbors' rmb rows
        const int sub = tid & 7;
        const int e0 = ptr[grow];
        const int end2 = ptr[grow + 1];
        float q0 = FLTMAX, q1 = FLTMAX, q2 = FLTMAX;
        for (int e = e0 + sub; e < end2; e += 8) {
            const float* rr = rmb + (size_t)csr[e] * 3;
            q0 = fminf(q0, rr[0]);
            q1 = fminf(q1, rr[1]);
            q2 = fminf(q2, rr[2]);
        }
#pragma unroll
        for (int off = 1; off < 8; off <<= 1) {
            q0 = fminf(q0, __shfl_xor(q0, off));
            q1 = fminf(q1, __shfl_xor(q1, off));
            q2 = fminf(q2, __shfl_xor(q2, off));
        }
        if (sub == 0) {
            const bool em = (e0 == end2);
            Rsh[sr * 4 + 0] = em ? 0.f : q0;
            Rsh[sr * 4 + 1] = em ? 0.f : q1;
            Rsh[sr * 4 + 2] = em ? 0.f : q2;
            Msh[sr * 4 + 0] = rmb[(size_t)grow * 3 + 0];
            Msh[sr * 4 + 1] = rmb[(size_t)grow * 3 + 1];
            Msh[sr * 4 + 2] = rmb[(size_t)grow * 3 + 2];
        }
    }
    __syncthreads();
    const int ct = tid % CT;
    const int rt = tid / CT;
    const int col = ct * 4;
    const int row0 = base + rt * 4;
    float4 acc[4] = {};
#pragma unroll 2
    for (int k0 = 0; k0 < 32; k0 += 4) {
        float4 wlv[4], wrv[4];
#pragma unroll
        for (int j = 0; j < 4; j++) {
            wlv[j] = *(const float4*)(wl + (size_t)(k0 + j) * DOUT + col);
            wrv[j] = *(const float4*)(wr + (size_t)(k0 + j) * DOUT + col);
        }
#pragma unroll
        for (int r = 0; r < 4; r++) {
            const float4 av = *(const float4*)(Ash + (rt * 4 + r) * LDW + k0);
            const float4 hv = *(const float4*)(Hsh + (rt * 4 + r) * LDW + k0);
#pragma unroll
            for (int j = 0; j < 4; j++) {
                const float aa = j == 0 ? av.x : j == 1 ? av.y : j == 2 ? av.z : av.w;
                const float bb = j == 0 ? hv.x : j == 1 ? hv.y : j == 2 ? hv.z : hv.w;
                acc[r].x += aa * wlv[j].x + bb * wrv[j].x;
                acc[r].y += aa * wlv[j].y + bb * wrv[j].y;
                acc[r].z += aa * wlv[j].z + bb * wrv[j].z;
                acc[r].w += aa * wlv[j].w + bb * wrv[j].w;
            }
        }
    }
#pragma unroll
    for (int k = 0; k < 3; k++) {
        const float4 wlv = *(const float4*)(wl + (size_t)(32 + k) * DOUT + col);
        const float4 wrv = *(const float4*)(wr + (size_t)(32 + k) * DOUT + col);
#pragma unroll
        for (int r = 0; r < 4; r++) {
            const float a = Rsh[(rt * 4 + r) * 4 + k];
            const float b = Msh[(rt * 4 + r) * 4 + k];
            acc[r].x += a * wlv.x + b * wrv.x;
            acc[r].y += a * wlv.y + b * wrv.y;
            acc[r].z += a * wlv.z + b * wrv.z;
            acc[r].w += a * wlv.w + b * wrv.w;
        }
    }
    const float4 bv = *(const float4*)(bl + col);
    float cs[4] = {}, cq[4] = {};
#pragma unroll
    for (int r = 0; r < 4; r++) {
        if (row0 + r < n) {
            float4 o = acc[r];
            o.x += bv.x; o.y += bv.y; o.z += bv.z; o.w += bv.w;
            *(float4*)(out + (size_t)(row0 + r) * DOUT + col) = o;
            cs[0] += o.x; cq[0] += o.x * o.x;
            cs[1] += o.y; cq[1] += o.y * o.y;
            cs[2] += o.z; cq[2] += o.z * o.z;
            cs[3] += o.w; cq[3] += o.w * o.w;
        }
    }
    __syncthreads();
#pragma unroll
    for (int j = 0; j < 4; j++) Ash[tid * 4 + j] = cs[j];
    __syncthreads();
    if (tid < CT) {
#pragma unroll
        for (int j = 0; j < 4; j++) {
            float s = 0.f;
#pragma unroll
            for (int k = 0; k < 8; k++) s += Ash[(tid + k * CT) * 4 + j];
            bpart[(size_t)blockIdx.x * 256 + tid * 4 + j] = s;
        }
    }
    __syncthreads();
#pragma unroll
    for (int j = 0; j < 4; j++) Ash[tid * 4 + j] = cq[j];
    __syncthreads();
    if (tid < CT) {
#pragma unroll
        for (int j = 0; j < 4; j++) {
            float s = 0.f;
#pragma unroll
            for (int k = 0; k < 8; k++) s += Ash[(tid + k * CT) * 4 + j];
            bpart[(size_t)blockIdx.x * 256 + 128 + tid * 4 + j] = s;
        }
    }
}

// ---- reduce per-block partials into stats (s | s2), width = 2*D ----
__global__ __launch_bounds__(256) void reduce_part_k(
    const float* __restrict__ bpart, float* __restrict__ stats,
    int nb, int width) {
    const int c = threadIdx.x;
    if (c >= width) return;
    float s = 0.f;
    for (int k = blockIdx.x; k < nb; k += gridDim.x)
        s += bpart[(size_t)k * width + c];
    atomicAdd(&stats[c], s);
}

// ====== rm head fused: gather(h2,D=64) + 64->3 linear + log_softmax + labels ======
// gather uses sign-folded min; BN coef inlined from stats2.
__global__ __launch_bounds__(256) void rm_fused_k(
    const float* __restrict__ h2, const float* __restrict__ stats,
    const float* __restrict__ g, const float* __restrict__ be,
    const int* __restrict__ ptr, const int* __restrict__ csr,
    const float* __restrict__ wl, const float* __restrict__ bl,
    const float* __restrict__ wr, float* __restrict__ rmb,
    float* __restrict__ ls_out, float* __restrict__ lab, float invN, int n) {
    const int lane = threadIdx.x & 63;
    const int node = (blockIdx.x * 256 + threadIdx.x) >> 6;
    if (node >= n) return;
    float a, b;
    bncoef(stats[lane], stats[64 + lane], g[lane], be[lane], invN, a, b);
    const u32 sm = (a < 0.f) ? 0x80000000u : 0u;
    int e = ptr[node];
    const int end = ptr[node + 1];
    const bool empty = (e == end);
    float m = FLTMAX;
    for (; e + 15 < end; e += 16) {
        int s[16];
#pragma unroll
        for (int j = 0; j < 16; j++) s[j] = csr[e + j];
        float v[16];
#pragma unroll
        for (int j = 0; j < 16; j++) v[j] = h2[(size_t)s[j] * 64 + lane];
#pragma unroll
        for (int j = 0; j < 16; j++) m = sfmin(m, v[j], sm);
    }
    for (; e + 3 < end; e += 4) {
        int s[4];
#pragma unroll
        for (int j = 0; j < 4; j++) s[j] = csr[e + j];
        float v[4];
#pragma unroll
        for (int j = 0; j < 4; j++) v[j] = h2[(size_t)s[j] * 64 + lane];
#pragma unroll
        for (int j = 0; j < 4; j++) m = sfmin(m, v[j], sm);
    }
    for (; e < end; e++) m = sfmin(m, h2[(size_t)csr[e] * 64 + lane], sm);
    const float mv = empty ? 0.f : trf(sdec(m, sm), a, b);
    const float hv = trf(h2[(size_t)node * 64 + lane], a, b);
    float c0 = mv * wl[lane * 3 + 0] + hv * wr[lane * 3 + 0];
    float c1 = mv * wl[lane * 3 + 1] + hv * wr[lane * 3 + 1];
    float c2 = mv * wl[lane * 3 + 2] + hv * wr[lane * 3 + 2];
#pragma unroll
    for (int off = 1; off < 64; off <<= 1) {
        c0 += __shfl_xor(c0, off);
        c1 += __shfl_xor(c1, off);
        c2 += __shfl_xor(c2, off);
    }
    const float r0 = c0 + bl[0], r1 = c1 + bl[1], r2 = c2 + bl[2];
    if (lane < 3) {
        const float r = lane == 0 ? r0 : lane == 1 ? r1 : r2;
        rmb[(size_t)node * 3 + lane] = r;
        const float mx = fmaxf(r0, fmaxf(r1, r2));
        const float lse = mx + logf(expf(r0 - mx) + expf(r1 - mx) + expf(r2 - mx));
        ls_out[(size_t)node * 3 + lane] = r - lse;
        if (lane == 0) lab[node] = (r2 > r0 && r2 > r1) ? 1.f : 0.f;
    }
}

// ====== final heads: wave-per-node, coalesced + shuffle reduce; coef inlined ======
__global__ __launch_bounds__(256) void final_k(
    const float* __restrict__ rtmd, const float* __restrict__ stats,
    const float* __restrict__ gR, const float* __restrict__ bR,
    const float* __restrict__ gM, const float* __restrict__ bM,
    const float* __restrict__ rtw, const float* __restrict__ rtb,
    const float* __restrict__ mdw, const float* __restrict__ mdb,
    const float* __restrict__ lab, float* __restrict__ out_rt,
    float* __restrict__ out_md, float invN, int n) {
    const int lane = threadIdx.x & 63;
    const int node = (blockIdx.x * 256 + threadIdx.x) >> 6;
    if (node >= n) return;
    float aR, bRc, aM, bMc;
    bncoef(stats[lane], stats[128 + lane], gR[lane], bR[lane], invN, aR, bRc);
    bncoef(stats[64 + lane], stats[192 + lane], gM[lane], bM[lane], invN, aM, bMc);
    const float* rr = rtmd + (size_t)node * 128;
    float a = trf(rr[lane], aR, bRc) * rtw[lane];
    float b = trf(rr[64 + lane], aM, bMc) * mdw[lane];
#pragma unroll
    for (int off = 1; off < 64; off <<= 1) {
        a += __shfl_xor(a, off);
        b += __shfl_xor(b, off);
    }
    if (lane == 0) {
        const float l = lab[node];
        out_rt[node] = (a + rtb[0]) * l;
        out_md[node] = (b + mdb[0]) * l;
    }
}

extern "C" void kernel_launch(void* const* d_in, const int* in_sizes, int n_in,
                              void* d_out, int out_size, void* d_ws, size_t ws_size,
                              hipStream_t stream) {
    const float* x = (const float*)d_in[0];
    const int* ei = (const int*)d_in[1];
    const int E = in_sizes[1] / 2;
    const int n = in_sizes[0] / 32;
    const int* src = ei;
    const int* dst = ei + E;

    const float* rm1_wl = (const float*)d_in[2];
    const float* rm1_bl = (const float*)d_in[3];
    const float* rm1_wr = (const float*)d_in[4];
    const float* rmn1_g = (const float*)d_in[5];
    const float* rmn1_b = (const float*)d_in[6];
    const float* rm2_wl = (const float*)d_in[7];
    const float* rm2_bl = (const float*)d_in[8];
    const float* rm2_wr = (const float*)d_in[9];
    const float* rmn2_g = (const float*)d_in[10];
    const float* rmn2_b = (const float*)d_in[11];
    const float* rm4_wl = (const float*)d_in[12];
    const float* rm4_bl = (const float*)d_in[13];
    const float* rm4_wr = (const float*)d_in[14];
    const float* sh1_wl = (const float*)d_in[15];
    const float* sh1_bl = (const float*)d_in[16];
    const float* sh1_wr = (const float*)d_in[17];
    const float* shn1_g = (const float*)d_in[18];
    const float* shn1_b = (const float*)d_in[19];
    const float* rt1_wl = (const float*)d_in[20];
    const float* rt1_bl = (const float*)d_in[21];
    const float* rt1_wr = (const float*)d_in[22];
    const float* rtn1_g = (const float*)d_in[23];
    const float* rtn1_b = (const float*)d_in[24];
    const float* rt3_w = (const float*)d_in[25];
    const float* rt3_b = (const float*)d_in[26];
    const float* md1_wl = (const float*)d_in[27];
    const float* md1_bl = (const float*)d_in[28];
    const float* md1_wr = (const float*)d_in[29];
    const float* mdn1_g = (const float*)d_in[30];
    const float* mdn1_b = (const float*)d_in[31];
    const float* md3_w = (const float*)d_in[32];
    const float* md3_b = (const float*)d_in[33];

    // workspace layout; shbuf serves as fp32 aggB (layer 2), then bf16 Acat (dual)
    char* w = (char*)d_ws;
    float* aggX  = (float*)w; w += (size_t)n * 32 * 4;
    float* h1    = (float*)w; w += (size_t)n * 128 * 4;   // h1 raw, later h3 raw
    char*  shbuf = w;         w += (size_t)n * 512;       // aggB fp32 [n][128] | Acat bf16 [n][256]
    float* h2rt  = (float*)w; w += (size_t)n * 128 * 4;   // h2 [n][64], later rtmd [n][128]
    float* rmb   = (float*)w; w += (size_t)n * 3 * 4;
    float* aggR  = (float*)w; w += (size_t)n * 3 * 4;     // (unused, kept for layout)
    float* lab   = (float*)w; w += (size_t)n * 4;
    float* stats = (float*)w; w += 1024 * 4;
    float* coef  = (float*)w; w += 1024 * 4;
    u16*   WTD   = (u16*)w;   w += (size_t)128 * 256 * 2;
    int* ptr  = (int*)w; w += (size_t)(n + 1) * 4;
    int* pos  = (int*)w; w += (size_t)n * 4;
    int* bsum = (int*)w; w += 1024 * 4;
    int* csr  = (int*)w; w += (size_t)E * 4;

    float* aggB = (float*)shbuf;
    u16*   Acat = (u16*)shbuf;
    float* h2 = h2rt;
    float* rtmd = h2rt;
    float* stats1 = stats, *stats2 = stats + 256, *statsSh = stats + 512, *statsD = stats + 768;
    float* coef1 = coef;   // exported by gather_min128 block 0, read by linear2

    // stats-partial buffers reuse dead regions (stream-ordered, no ws growth)
    float* bp1  = (float*)shbuf;
    float* bp2  = rmb;
    float* bpSh = (float*)shbuf;
    float* bpD  = rmb;

    float* out = (float*)d_out;
    float* out_ls = out;
    float* out_rt = out + (size_t)3 * n;
    float* out_md = out + (size_t)4 * n;

    const float invN = 1.f / (float)n;
    auto cdiv = [](int a, int b) { return (a + b - 1) / b; };
    const int nb = cdiv(n, 256);
    const int nb32 = cdiv(n, 32);
    const int nb64 = cdiv(n, 64);
    const int lo_step = cdiv(n, 8);

    hipMemsetAsync(stats, 0, 1024 * 4, stream);
    hipMemsetAsync(pos, 0, (size_t)n * 4, stream);

    // ---- CSR build + dual-weight prep
    hist_k<<<cdiv(E, 256), 256, 0, stream>>>(dst, pos, E);
    wprep_dual_k<<<128, 256, 0, stream>>>(rt1_wl, rt1_wr, md1_wl, md1_wr, WTD);
    scan_block_k<<<nb, 256, 0, stream>>>(pos, ptr, bsum, n);
    scan_add_k<<<nb, 256, 0, stream>>>(ptr, pos, bsum, n, E);
    csr_fill_part_k<<<cdiv(E, 256) * 8, 256, 0, stream>>>(src, dst, pos, csr, E, lo_step);

    // ---- layer 1 (fp32): agg(x) -> linear (fused stats -> bpart) -> h1
    gather_min32_k<<<cdiv(n, 8), 256, 0, stream>>>(x, ptr, csr, aggX, n);
    linear1s_k<<<nb32, 256, 0, stream>>>(aggX, x, rm1_wl, rm1_bl, rm1_wr, h1, bp1, n);
    reduce_part_k<<<64, 256, 0, stream>>>(bp1, stats1, nb32, 256);

    // ---- layer 2 (fp32, label-critical): gather(bnrelu(h1)) [coef1 inline+export]
    gather_min128_k<<<cdiv(n, 4), 256, 0, stream>>>(h1, ptr, csr, stats1, rmn1_g, rmn1_b,
                                                    coef1, aggB, invN, n);
    linear2_k<<<nb64, 256, 0, stream>>>(aggB, h1, coef1, rm2_wl, rm2_bl, rm2_wr, h2, bp2, n);
    reduce_part_k<<<64, 256, 0, stream>>>(bp2, stats2, nb64, 128);

    // ---- rm head (fp32): fused gather + linear + log_softmax + labels [coef2 inline]
    rm_fused_k<<<cdiv(n, 4), 256, 0, stream>>>(h2, stats2, rmn2_g, rmn2_b, ptr, csr,
                                               rm4_wl, rm4_bl, rm4_wr, rmb, out_ls, lab, invN, n);

    // ---- sh1 (fp32): linear concat([x,rm]) with fused rm-gather -> h3 (h1 buf)
    linear_shs_k<<<nb32, 256, 0, stream>>>(aggX, x, rmb, ptr, csr,
                                           sh1_wl, sh1_bl, sh1_wr, h1, bpSh, n);
    reduce_part_k<<<64, 256, 0, stream>>>(bpSh, statsSh, nb32, 256);

    // ---- dual rt/md (bf16 MFMA): convert [coefSh inline] -> gather -> GEMM
    convert_k<<<cdiv(n * 32, 256), 256, 0, stream>>>(h1, statsSh, shn1_g, shn1_b, Acat, invN, n);
    gather_bf_k<<<cdiv(n, 8), 256, 0, stream>>>(Acat, ptr, csr, n);
    gemm_bf_k<<<nb64, 256, 0, stream>>>(Acat, WTD, rt1_bl, md1_bl, rtmd, bpD, n);
    reduce_part_k<<<64, 256, 0, stream>>>(bpD, statsD, nb64, 256);

    // ---- final heads [coefRt/Md inline]
    final_k<<<cdiv(n, 4), 256, 0, stream>>>(rtmd, statsD, rtn1_g, rtn1_b, mdn1_g, mdn1_b,
                                            rt3_w, rt3_b, md3_w, md3_b, lab,
                                            out_rt, out_md, invN, n);
}